// Round 2
// baseline (898.103 us; speedup 1.0000x reference)
//
#include <hip/hip_runtime.h>
#include <cmath>

// ---------------------------------------------------------------------------
// Backbone forward (B=32, L=512, D=321, P=16, N=32, dm=256, pred=96), fp32.
// ---------------------------------------------------------------------------

#define BB   32
#define LL   512
#define DD   321
#define PRED 96
#define M_ROWS (BB*DD)          // 10272 rows of length 512

__device__ __forceinline__ float gelu_f(float x){
  return 0.5f*x*(1.0f + erff(x*0.70710678118654752440f));
}
__device__ __forceinline__ float sigmoid_f(float x){
  return 1.0f/(1.0f+expf(-x));
}

// ---------------- workspace layout (floats) --------------------------------
constexpr size_t OFF_CO   = 0;                        // Co[512][512]
constexpr size_t OFF_COT  = OFF_CO   + 512*512;       // CoT[512][512]
constexpr size_t OFF_DVEC = OFF_COT  + 512*512;       // dvec[512]
constexpr size_t OFF_CATT = OFF_DVEC + 512;           // catt[512]
constexpr size_t OFF_FC1T = OFF_CATT + 512;           // fc1T[96][512]
constexpr size_t OFF_WEFFT= OFF_FC1T + 96*512;        // WeffT[96][512]
constexpr size_t OFF_CRES = OFF_WEFFT+ 96*512;        // cres[96] (pad 128)
constexpr size_t OFF_MP   = OFF_CRES + 128;           // M'[32][16][16]
constexpr size_t OFF_C2P  = OFF_MP   + 32*256;        // c2'[32][16]
constexpr size_t OFF_AF   = OFF_C2P  + 512;           // Af[321] pad 384
constexpr size_t OFF_CF   = OFF_AF   + 384;
constexpr size_t OFF_DNS  = OFF_CF   + 384;
constexpr size_t OFF_BF   = OFF_DNS  + 384;
constexpr size_t OFF_EN   = OFF_BF   + 384;           // energy[10272] pad 10368
constexpr size_t OFF_NE   = OFF_EN   + 10368;         // ne[10272]
constexpr size_t OFF_THR  = OFF_NE   + 10368;         // thr scalar (pad 64)
constexpr size_t OFF_ZDP  = OFF_THR  + 64;            // zdpre[10272]
constexpr size_t OFF_ATT1 = OFF_ZDP  + 10368;         // att1[10272]
constexpr size_t OFF_XT   = OFF_ATT1 + 10368;         // xt  [10272][512]
constexpr size_t OFF_ZDCT = OFF_XT   + (size_t)M_ROWS*512; // zdct (reused z2f)
constexpr size_t OFF_Z1   = OFF_ZDCT + (size_t)M_ROWS*512; // z1 (reused zf)
constexpr size_t OFF_Z2   = OFF_Z1   + (size_t)M_ROWS*512;
constexpr size_t OFF_Z1C  = OFF_Z2   + (size_t)M_ROWS*512;
constexpr size_t OFF_H    = OFF_Z1C  + (size_t)M_ROWS*512; // h[10272][96]
constexpr size_t OFF_ZRES = OFF_H    + (size_t)M_ROWS*96;  // zres[10272][96]
constexpr size_t WS_FLOATS= OFF_ZRES + (size_t)M_ROWS*96;

// ---------------- precompute: DCT matrices (row-coalesced both ways) --------
__global__ __launch_bounds__(256)
void k0_dct(float* __restrict__ Co, float* __restrict__ CoT, float* __restrict__ dvec,
            float* __restrict__ catt, const float* __restrict__ attw)
{
  const float PI_F = 3.14159265358979323846f;     // rounds to f32 pi (matches jnp)
  int b = blockIdx.x;                             // row index for both outputs
  // Co row b: Co[b][l] = cos(pi*(2l+1)*b/1024) * ck(b)
  float ckb = (b==0) ? (1.0f/sqrtf(512.0f)) : sqrtf(2.0f/512.0f);
  for (int l=threadIdx.x; l<512; l+=256){
    float a1 = PI_F * (float)(2*l+1);
    float a2 = a1 * (float)b;
    float c  = cosf(a2 * (1.0f/1024.0f)) * ckb;
    Co[b*512+l] = c;
  }
  // CoT row b: CoT[b][k] = Co[k][b] = cos(pi*(2b+1)*k/1024) * ck(k)
  for (int k=threadIdx.x; k<512; k+=256){
    float ckk = (k==0) ? (1.0f/sqrtf(512.0f)) : sqrtf(2.0f/512.0f);
    float a1 = PI_F * (float)(2*b+1);
    float a2 = a1 * (float)k;
    CoT[b*512+k] = cosf(a2 * (1.0f/1024.0f)) * ckk;
  }
  if (threadIdx.x==0) dvec[b] = (b==0) ? 2.0f*sqrtf(512.0f) : sqrtf(2.0f*512.0f);
  if (b==0){
    for (int l=threadIdx.x; l<512; l+=256){
      float sacc=0.f;
      for (int j=0;j<5;j++){
        float ckj = (j==0)?(1.0f/sqrtf(512.0f)):sqrtf(2.0f/512.0f);
        float a1 = PI_F*(float)(2*l+1);
        float a2 = a1*(float)j;
        sacc += cosf(a2 * (1.0f/1024.0f))*ckj*attw[j];
      }
      catt[l]=sacc;
    }
  }
}

// ---------------- precompute: Weff^T, fc1^T, cres ---------------------------
__global__ __launch_bounds__(128)
void k0_weff(const float* __restrict__ embed_w, const float* __restrict__ embed_b,
             const float* __restrict__ lrw, const float* __restrict__ lrb,
             const float* __restrict__ fc1_w,
             float* __restrict__ fc1T, float* __restrict__ WeffT, float* __restrict__ cres)
{
  int l = blockIdx.x; int pr = threadIdx.x;
  if (l < 512){
    if (pr < 96){
      int n = l>>4, p = l&15;
      float a0=0.f,a1=0.f,a2=0.f,a3=0.f;     // 4-way ILP
      for (int j=0;j<256;j+=4){
        a0 = fmaf(embed_w[p*256+j+0], lrw[((size_t)(n*256+j+0))*96+pr], a0);
        a1 = fmaf(embed_w[p*256+j+1], lrw[((size_t)(n*256+j+1))*96+pr], a1);
        a2 = fmaf(embed_w[p*256+j+2], lrw[((size_t)(n*256+j+2))*96+pr], a2);
        a3 = fmaf(embed_w[p*256+j+3], lrw[((size_t)(n*256+j+3))*96+pr], a3);
      }
      WeffT[pr*512 + l] = (a0+a1)+(a2+a3);
      fc1T [pr*512 + l] = fc1_w[l*96+pr];
    }
  } else {                               // block 512 -> cres
    if (pr < 96){
      float a0=lrb[pr], a1=0.f, a2=0.f, a3=0.f;  // 4-way ILP over 8192 terms
      for (int i=0;i<8192;i+=4){
        a0 = fmaf(embed_b[(i+0) & 255], lrw[(size_t)(i+0)*96+pr], a0);
        a1 = fmaf(embed_b[(i+1) & 255], lrw[(size_t)(i+1)*96+pr], a1);
        a2 = fmaf(embed_b[(i+2) & 255], lrw[(size_t)(i+2)*96+pr], a2);
        a3 = fmaf(embed_b[(i+3) & 255], lrw[(size_t)(i+3)*96+pr], a3);
      }
      cres[pr]=(a0+a1)+(a2+a3);
    }
  }
}

// ---------------- precompute: patch matrix M' (+BN fold) --------------------
__global__ __launch_bounds__(256)
void k0_depth(const float* __restrict__ embed_w, const float* __restrict__ embed_b,
              const float* __restrict__ drw, const float* __restrict__ drb,
              const float* __restrict__ dcw, const float* __restrict__ dcb,
              const float* __restrict__ png, const float* __restrict__ pnb,
              const float* __restrict__ pnm, const float* __restrict__ pnv,
              float* __restrict__ Mp, float* __restrict__ c2p)
{
  int n = blockIdx.x; int tid = threadIdx.x;
  int q = tid>>4, p = tid&15;
  float acc = 0.f;                       // depth_conv part
  for (int j=0;j<16;j++)  acc = fmaf(embed_w[q*256 + p*16 + j], dcw[n*16+j], acc);
  float wtr = 0.f;                       // time_res part
  for (int j=0;j<256;j++) wtr = fmaf(embed_w[q*256 + j], drw[j*16+p], wtr);
  float sn = png[n]/sqrtf(pnv[n]+1e-5f);
  Mp[n*256 + q*16 + p] = (acc + wtr) * sn;
  if (q==0){
    float c = dcb[n];
    for (int j=0;j<16;j++)  c = fmaf(embed_b[p*16+j], dcw[n*16+j], c);
    float ctr = drb[p];
    for (int j=0;j<256;j++) ctr = fmaf(embed_b[j], drw[j*16+p], ctr);
    c += ctr;
    c2p[n*16+p] = (c - pnm[n])*sn + pnb[n];
  }
}

// ---------------- precompute: per-channel BN/conv1 folds --------------------
__global__ void k0_fold(const float* __restrict__ w1, const float* __restrict__ b1,
                        const float* __restrict__ g,  const float* __restrict__ bbq,
                        const float* __restrict__ mq, const float* __restrict__ vq,
                        float* __restrict__ Af, float* __restrict__ Cf,
                        float* __restrict__ dns, float* __restrict__ Bf)
{
  int d = blockIdx.x*256 + threadIdx.x;
  if (d >= DD) return;
  float s  = g[d]/sqrtf(vq[d]+1e-5f);
  float bf = bbq[d] - mq[d]*s;
  dns[d]=s; Bf[d]=bf; Af[d]=s*w1[d]; Cf[d]=bf*w1[d]+b1[d];
}

// ---------------- transpose x[B,L,D] -> xt[B*D,512] -------------------------
__global__ __launch_bounds__(256)
void k1_transpose(const float* __restrict__ x, float* __restrict__ xt)
{
  int b = blockIdx.z; int l0 = blockIdx.y*32; int d0 = blockIdx.x*32;
  __shared__ float t[32][33];
  int tid=threadIdx.x; int j = tid&31, i0 = tid>>5;
  for (int ii=0; ii<32; ii+=8){
    int l = l0 + i0+ii; int d = d0 + j;
    t[i0+ii][j] = (d<DD) ? x[((size_t)b*512 + l)*DD + d] : 0.f;
  }
  __syncthreads();
  for (int ii=0; ii<32; ii+=8){
    int d = d0 + i0+ii; int l = l0 + j;
    if (d<DD) xt[((size_t)b*DD+d)*512 + l] = t[j][i0+ii];
  }
}

// ---------------- generic NT GEMM: C[r,c] = sum_k A[r,k]*B[c,k] -------------
// OP=0: *=dvec[c], store zdct.       OP=1: + xt*w1+b1 (freq_res), store z1.
// OP=2: gelu(acc*dvec[c])*Af+Cf.     OP=3: gelu(acc+fc1_b[c]) -> h (96 cols).
// OP=4: acc + cres[c] -> zres (96 cols).
template<int OP>
__global__ __launch_bounds__(256)
void gemm_nt(const float* __restrict__ A, const float* __restrict__ B,
             float* __restrict__ C, int M, int Ncols, int ldc,
             const float* __restrict__ p0, const float* __restrict__ p1,
             const float* __restrict__ p2, const float* __restrict__ p3)
{
  __shared__ float As[32][132];   // +4 pad keeps 16B alignment, spreads banks
  __shared__ float Bs[32][68];
  const int tid = threadIdx.x;
  const int tx = tid & 15, ty = tid >> 4;
  const int rb = blockIdx.y * 128, cb = blockIdx.x * 64;

  float acc[8][4];
  #pragma unroll
  for (int i=0;i<8;i++)
    #pragma unroll
    for (int j=0;j<4;j++) acc[i][j]=0.f;

  for (int kb=0; kb<512; kb+=32){
    #pragma unroll
    for (int i=0;i<4;i++){
      int idx = tid + i*256;
      int row = idx >> 3, k4 = (idx & 7)*4;
      float4 v = make_float4(0.f,0.f,0.f,0.f);
      int r = rb + row;
      if (r < M) v = *reinterpret_cast<const float4*>(A + (size_t)r*512 + kb + k4);
      As[k4+0][row]=v.x; As[k4+1][row]=v.y; As[k4+2][row]=v.z; As[k4+3][row]=v.w;
    }
    #pragma unroll
    for (int i=0;i<2;i++){
      int idx = tid + i*256;
      int row = idx >> 3, k4 = (idx & 7)*4;
      float4 v = make_float4(0.f,0.f,0.f,0.f);
      int c = cb + row;
      if (c < Ncols) v = *reinterpret_cast<const float4*>(B + (size_t)c*512 + kb + k4);
      Bs[k4+0][row]=v.x; Bs[k4+1][row]=v.y; Bs[k4+2][row]=v.z; Bs[k4+3][row]=v.w;
    }
    __syncthreads();
    #pragma unroll
    for (int kk=0; kk<32; kk++){
      const float4 a0 = *reinterpret_cast<const float4*>(&As[kk][ty*8]);
      const float4 a1 = *reinterpret_cast<const float4*>(&As[kk][ty*8+4]);
      const float4 b0 = *reinterpret_cast<const float4*>(&Bs[kk][tx*4]);
      float av[8]={a0.x,a0.y,a0.z,a0.w,a1.x,a1.y,a1.z,a1.w};
      float bv[4]={b0.x,b0.y,b0.z,b0.w};
      #pragma unroll
      for (int i=0;i<8;i++)
        #pragma unroll
        for (int j=0;j<4;j++) acc[i][j]=fmaf(av[i],bv[j],acc[i][j]);
    }
    __syncthreads();
  }

  #pragma unroll
  for (int i=0;i<8;i++){
    const int r = rb + ty*8 + i;
    const bool rok = (r < M);
    if constexpr (OP==0){
      if (rok){
        #pragma unroll
        for (int j=0;j<4;j++){
          int c = cb + tx*4 + j;
          C[(size_t)r*ldc + c] = acc[i][j]*p0[c];          // p0 = dvec
        }
      }
    } else if constexpr (OP==1){
      if (rok){
        int d = r % DD;
        float w = p0[d], bo = p1[d];                        // conv1_w / conv1_b
        #pragma unroll
        for (int j=0;j<4;j++){
          int c = cb + tx*4 + j;
          C[(size_t)r*ldc + c] = acc[i][j] + p2[(size_t)r*512 + c]*w + bo;  // p2 = xt
        }
      }
    } else if constexpr (OP==2){
      if (rok){
        int d = r % DD;
        float w = p0[d], bo = p1[d];                        // Af / Cf
        #pragma unroll
        for (int j=0;j<4;j++){
          int c = cb + tx*4 + j;
          float t = acc[i][j]*p3[c];                        // p3 = dvec
          C[(size_t)r*ldc + c] = gelu_f(t)*w + bo;
        }
      }
    } else if constexpr (OP==3){
      if (rok){
        #pragma unroll
        for (int j=0;j<4;j++){
          int c = cb + tx*4 + j;
          if (c < Ncols) C[(size_t)r*ldc + c] = gelu_f(acc[i][j] + p0[c]); // p0=fc1_b
        }
      }
    } else {   // OP==4
      if (rok){
        #pragma unroll
        for (int j=0;j<4;j++){
          int c = cb + tx*4 + j;
          if (c < Ncols) C[(size_t)r*ldc + c] = acc[i][j] + p0[c];        // p0=cres
        }
      }
    }
  }
}

// ---------------- energy per row (deterministic) ----------------------------
__global__ __launch_bounds__(256)
void k_energy(const float* __restrict__ zdct, float* __restrict__ energy)
{
  int r=blockIdx.x, tid=threadIdx.x;
  __shared__ float rbuf[256];
  float acc=0.f;
  for (int k=tid;k<512;k+=256){ float v=zdct[(size_t)r*512+k]; acc=fmaf(v,v,acc); }
  rbuf[tid]=acc; __syncthreads();
  for (int st=128;st>0;st>>=1){ if(tid<st) rbuf[tid]+=rbuf[tid+st]; __syncthreads(); }
  if (tid==0) energy[r]=rbuf[0];
}

// ---------------- median over D per batch, ne = e/(med+1e-6) ----------------
__global__ __launch_bounds__(256)
void k3_median(const float* __restrict__ energy, float* __restrict__ ne)
{
  int b = blockIdx.x, tid=threadIdx.x;
  __shared__ float e[DD];
  __shared__ float medv;
  for (int i=tid;i<DD;i+=256) e[i]=energy[b*DD+i];
  __syncthreads();
  for (int i=tid;i<DD;i+=256){
    float v=e[i]; int lt=0, eq=0;
    for (int j=0;j<DD;j++){ float u=e[j]; lt += (u<v); eq += (u==v); }
    if (lt<=160 && 160<lt+eq) medv=v;      // 0-based rank 160 of 321
  }
  __syncthreads();
  float den = medv + 1e-6f;
  for (int i=tid;i<DD;i+=256) ne[b*DD+i] = e[i]/den;
}

// ---------------- quantile via radix select (2 ranks + lerp) ----------------
__global__ __launch_bounds__(1024)
void k3_thr(const float* __restrict__ ne, const float* __restrict__ thrin,
            float* __restrict__ out)
{
  __shared__ int hist[256];
  __shared__ unsigned sPrefix; __shared__ int sRank;
  int tid = threadIdx.x;
  float q = fminf(fmaxf(thrin[0],0.f),1.f);
  float pos = q * (float)(M_ROWS-1);
  int lo = (int)floorf(pos); int hi = (int)ceilf(pos);
  float frac = pos - floorf(pos);
  float vals[2];
  for (int s=0;s<2;s++){
    int rank = s ? hi : lo;
    unsigned prefix=0, pmask=0;
    for (int pass=0; pass<4; pass++){
      int shift = 24 - 8*pass;
      if (tid<256) hist[tid]=0;
      __syncthreads();
      for (int i=tid;i<M_ROWS;i+=1024){
        unsigned u = __float_as_uint(ne[i]);      // ne >= 0 -> bits order = value order
        if ((u & pmask)==prefix) atomicAdd(&hist[(u>>shift)&255u],1);
      }
      __syncthreads();
      if (tid==0){
        int cum=0;
        for (int bkt=0;bkt<256;bkt++){
          int c=hist[bkt];
          if (cum + c > rank){ sPrefix = prefix | ((unsigned)bkt<<(unsigned)shift); sRank = rank - cum; break; }
          cum += c;
        }
      }
      __syncthreads();
      prefix = sPrefix; rank = sRank; pmask |= (0xFFu<<(unsigned)shift);
      __syncthreads();
    }
    vals[s] = __uint_as_float(prefix);
  }
  if (tid==0) out[0] = vals[0]*(1.0f-frac) + vals[1]*frac;
}

// ---------------- in-place transform of zdct before IDCT --------------------
__global__ void k4_pre(float* __restrict__ zdct, const float* __restrict__ ne,
                       const float* __restrict__ thr, const float* __restrict__ w1,
                       const float* __restrict__ b1, const float* __restrict__ dvec)
{
  size_t idx = (size_t)blockIdx.x*256 + threadIdx.x;   // over 10272*128 float4
  int r = (int)(idx>>7);
  int k0 = ((int)idx & 127)*4;
  float m  = (ne[r] > thr[0]) ? 1.f : 0.f;
  int d = r % DD;
  float w = w1[d]*m, bo = b1[d];
  float4 v = ((float4*)zdct)[idx];
  v.x = gelu_f(fmaf(v.x,w,bo))/dvec[k0+0];
  v.y = gelu_f(fmaf(v.y,w,bo))/dvec[k0+1];
  v.z = gelu_f(fmaf(v.z,w,bo))/dvec[k0+2];
  v.w = gelu_f(fmaf(v.w,w,bo))/dvec[k0+3];
  ((float4*)zdct)[idx]=v;
}

// ---------------- z2: per-patch 16x16 matmul + gelu -------------------------
__global__ __launch_bounds__(256)
void k5_z2(const float* __restrict__ xt, const float* __restrict__ Mp,
           const float* __restrict__ c2p, float* __restrict__ z2)
{
  int r = blockIdx.x, tid=threadIdx.x;
  __shared__ float row[512];
  for (int i=tid;i<512;i+=256) row[i]=xt[(size_t)r*512+i];
  __syncthreads();
  for (int idx=tid; idx<512; idx+=256){
    int n = idx>>4, p = idx&15;
    float acc = c2p[idx];
    const float* Mn = Mp + n*256 + p;
    #pragma unroll
    for (int qq=0;qq<16;qq++) acc = fmaf(row[n*16+qq], Mn[qq*16], acc);
    z2[(size_t)r*512+idx] = gelu_f(acc);
  }
}

// ---------------- fused convs / gates / z1c / att-dot -----------------------
__global__ __launch_bounds__(256)
void k7_fuse(const float* __restrict__ z1, const float* __restrict__ z2f,
             const float* __restrict__ z2, float* __restrict__ z1c,
             float* __restrict__ zdpre,
             const float* __restrict__ c2w, const float* __restrict__ c2b,
             const float* __restrict__ c3w, const float* __restrict__ c3b,
             const float* __restrict__ Af,  const float* __restrict__ Cf,
             const float* __restrict__ dns, const float* __restrict__ Bf,
             const float* __restrict__ catt)
{
  int r = blockIdx.x, tid=threadIdx.x;
  int d = r % DD;
  __shared__ float zrow[518];
  __shared__ float rbuf[256];
  for (int i=tid;i<518;i+=256){
    int l = i-3;
    zrow[i] = (l>=0 && l<512) ? z1[(size_t)r*512+l] : 0.f;
  }
  __syncthreads();
  float w2[5], w3[7];
  #pragma unroll
  for (int t=0;t<5;t++) w2[t]=c2w[d*5+t];
  #pragma unroll
  for (int t=0;t<7;t++) w3[t]=c3w[d*7+t];
  const float cb2=c2b[d], cb3=c3b[d];
  const float af=Af[d], cf=Cf[d], s=dns[d], bf=Bf[d];
  float dotacc=0.f;
  for (int l=tid;l<512;l+=256){
    float c5=cb2;
    #pragma unroll
    for (int t=0;t<5;t++) c5 = fmaf(zrow[l+t+1], w2[t], c5);   // pad-2 conv k=5
    float zr  = sigmoid_f(fmaf(gelu_f(c5),af,cf));
    float zgv = gelu_f(z2f[(size_t)r*512+l]*zr);
    float c7=cb3;
    #pragma unroll
    for (int t=0;t<7;t++) c7 = fmaf(zrow[l+t], w3[t], c7);     // pad-3 conv k=7
    float z1b = gelu_f(fmaf(c7,s,bf));
    float v = fmaf(zgv,s,bf) + z1b;                            // z1c = bnD(zg)+z1b
    z1c[(size_t)r*512+l]=v;
    dotacc = fmaf(v*z2[(size_t)r*512+l], catt[l], dotacc);
  }
  rbuf[tid]=dotacc; __syncthreads();
  for (int st=128;st>0;st>>=1){ if(tid<st) rbuf[tid]+=rbuf[tid+st]; __syncthreads(); }
  if (tid==0) zdpre[r]=rbuf[0];
}

// ---------------- attention scalar path + softmax over D --------------------
__global__ __launch_bounds__(256)
void k8_att(const float* __restrict__ zdpre, float* __restrict__ att1,
            const float* __restrict__ adwb, const float* __restrict__ acw,
            const float* __restrict__ acb,  const float* __restrict__ ag,
            const float* __restrict__ ab,   const float* __restrict__ am,
            const float* __restrict__ av)
{
  int b=blockIdx.x, t=threadIdx.x;
  __shared__ float sred[256];
  float vloc[2];
  float mx=-INFINITY;
  float sA = ag[0]/sqrtf(av[0]+1e-5f);
  #pragma unroll
  for (int ii=0;ii<2;ii++){
    int d=t+ii*256;
    float v=-INFINITY;
    if (d<DD){
      float zd = zdpre[b*DD+d] + adwb[0];
      zd = gelu_f(zd);
      zd = (zd-am[0])*sA + ab[0];
      zd = zd*acw[0] + acb[0];
      v=zd;
    }
    vloc[ii]=v; mx=fmaxf(mx,v);
  }
  sred[t]=mx; __syncthreads();
  for (int st=128;st>0;st>>=1){ if (t<st) sred[t]=fmaxf(sred[t],sred[t+st]); __syncthreads(); }
  float m=sred[0]; __syncthreads();
  float e0 = (t<DD)     ? expf(vloc[0]-m) : 0.f;
  float e1 = (t+256<DD) ? expf(vloc[1]-m) : 0.f;
  sred[t]=e0+e1; __syncthreads();
  for (int st=128;st>0;st>>=1){ if (t<st) sred[t]+=sred[t+st]; __syncthreads(); }
  float sum=sred[0];
  if (t<DD)     att1[b*DD+t]     = e0/sum;
  if (t+256<DD) att1[b*DD+t+256] = e1/sum;
}

// ---------------- zf = z1c*att + z2*(1-att) ---------------------------------
__global__ void k8b_zf(const float* __restrict__ z1c, const float* __restrict__ z2,
                       const float* __restrict__ att1, float* __restrict__ zf)
{
  size_t idx = (size_t)blockIdx.x*256 + threadIdx.x;   // over 10272*128 float4
  int r = (int)(idx>>7);
  float a = att1[r];
  float4 v1 = ((const float4*)z1c)[idx];
  float4 v2 = ((const float4*)z2)[idx];
  float4 o;
  o.x = v1.x*a + v2.x*(1.f-a);
  o.y = v1.y*a + v2.y*(1.f-a);
  o.z = v1.z*a + v2.z*(1.f-a);
  o.w = v1.w*a + v2.w*(1.f-a);
  ((float4*)zf)[idx]=o;
}

// ---------------- final: out = h@fc2 + fc2_b + zres, transposed store -------
__global__ __launch_bounds__(256)
void k9_final(const float* __restrict__ h, const float* __restrict__ zres,
              const float* __restrict__ fc2_w, const float* __restrict__ fc2_b,
              float* __restrict__ outF)
{
  int b = blockIdx.y; int d0 = blockIdx.x*32;
  __shared__ float f2[96*96];
  __shared__ float hs[32][97];
  __shared__ float zs[32][97];
  int tid=threadIdx.x;
  for (int i=tid;i<96*96;i+=256) f2[i]=fc2_w[i];
  for (int i=tid;i<32*96;i+=256){
    int dl = i/96, p = i%96; int d = d0+dl;
    float hv=0.f, zv=0.f;
    if (d<DD){ hv = h[((size_t)b*DD+d)*96+p]; zv = zres[((size_t)b*DD+d)*96+p]; }
    hs[dl][p]=hv; zs[dl][p]=zv;
  }
  __syncthreads();
  int tx = tid & 31, ty = tid >> 5;       // tx: d_local, ty: 0..7
  int d = d0+tx;
  float acc[12];
  #pragma unroll
  for (int kc=0;kc<12;kc++) acc[kc]=0.f;
  for (int p=0;p<96;p++){
    float hv = hs[tx][p];
    #pragma unroll
    for (int kc=0;kc<12;kc++) acc[kc] = fmaf(hv, f2[p*96 + ty + kc*8], acc[kc]);
  }
  if (d<DD){
    #pragma unroll
    for (int kc=0;kc<12;kc++){
      int c = ty + kc*8;
      outF[((size_t)b*96 + c)*DD + d] = acc[kc] + fc2_b[c] + zs[tx][c];
    }
  }
}

// ---------------------------------------------------------------------------
extern "C" void kernel_launch(void* const* d_in, const int* in_sizes, int n_in,
                              void* d_out, int out_size, void* d_ws, size_t ws_size,
                              hipStream_t stream)
{
  (void)in_sizes; (void)n_in; (void)out_size; (void)ws_size;
  const float* x        =(const float*)d_in[0];
  const float* conv1_w  =(const float*)d_in[1];
  const float* conv1_b  =(const float*)d_in[2];
  const float* conv2_w  =(const float*)d_in[3];
  const float* conv2_b  =(const float*)d_in[4];
  const float* conv3_w  =(const float*)d_in[5];
  const float* conv3_b  =(const float*)d_in[6];
  const float* dn_g     =(const float*)d_in[7];
  const float* dn_b     =(const float*)d_in[8];
  const float* dn_m     =(const float*)d_in[9];
  const float* dn_v     =(const float*)d_in[10];
  const float* pn_g     =(const float*)d_in[11];
  const float* pn_b     =(const float*)d_in[12];
  const float* pn_m     =(const float*)d_in[13];
  const float* pn_v     =(const float*)d_in[14];
  const float* embed_w  =(const float*)d_in[15];
  const float* embed_b  =(const float*)d_in[16];
  const float* lin_res_w=(const float*)d_in[17];
  const float* lin_res_b=(const float*)d_in[18];
  const float* depth_res_w=(const float*)d_in[19];
  const float* depth_res_b=(const float*)d_in[20];
  const float* depth_conv_w=(const float*)d_in[21];
  const float* depth_conv_b=(const float*)d_in[22];
  const float* threshold=(const float*)d_in[23];
  const float* att_dw_w =(const float*)d_in[24];
  const float* att_dw_b =(const float*)d_in[25];
  const float* att_conv_w=(const float*)d_in[26];
  const float* att_conv_b=(const float*)d_in[27];
  const float* att_g    =(const float*)d_in[28];
  const float* att_b    =(const float*)d_in[29];
  const float* att_m    =(const float*)d_in[30];
  const float* att_v    =(const float*)d_in[31];
  const float* fc1_w    =(const float*)d_in[32];
  const float* fc1_b    =(const float*)d_in[33];
  const float* fc2_w    =(const float*)d_in[34];
  const float* fc2_b    =(const float*)d_in[35];

  float* ws   = (float*)d_ws;
  float* Co   = ws + OFF_CO;
  float* CoT  = ws + OFF_COT;
  float* dvec = ws + OFF_DVEC;
  float* catt = ws + OFF_CATT;
  float* fc1T = ws + OFF_FC1T;
  float* WeffT= ws + OFF_WEFFT;
  float* cres = ws + OFF_CRES;
  float* Mp   = ws + OFF_MP;
  float* c2p  = ws + OFF_C2P;
  float* Af   = ws + OFF_AF;
  float* Cf   = ws + OFF_CF;
  float* dns  = ws + OFF_DNS;
  float* Bf   = ws + OFF_BF;
  float* energy=ws + OFF_EN;
  float* ne   = ws + OFF_NE;
  float* thr  = ws + OFF_THR;
  float* zdpre= ws + OFF_ZDP;
  float* att1 = ws + OFF_ATT1;
  float* xt   = ws + OFF_XT;
  float* zdct = ws + OFF_ZDCT;   // later reused as z2f
  float* z1   = ws + OFF_Z1;     // later reused as zf
  float* z2   = ws + OFF_Z2;
  float* z1c  = ws + OFF_Z1C;
  float* h    = ws + OFF_H;
  float* zres = ws + OFF_ZRES;

  // --- precompute ---
  k0_dct  <<<512, 256, 0, stream>>>(Co, CoT, dvec, catt, att_dw_w);
  k0_weff <<<513, 128, 0, stream>>>(embed_w, embed_b, lin_res_w, lin_res_b, fc1_w,
                                    fc1T, WeffT, cres);
  k0_depth<<<32, 256, 0, stream>>>(embed_w, embed_b, depth_res_w, depth_res_b,
                                   depth_conv_w, depth_conv_b, pn_g, pn_b, pn_m, pn_v,
                                   Mp, c2p);
  k0_fold <<<2, 256, 0, stream>>>(conv1_w, conv1_b, dn_g, dn_b, dn_m, dn_v,
                                  Af, Cf, dns, Bf);

  // --- transpose, DCT(x), mask stats ---
  k1_transpose<<<dim3(11,16,BB), 256, 0, stream>>>(x, xt);
  gemm_nt<0><<<dim3(8,81), 256, 0, stream>>>(xt, Co, zdct, M_ROWS, 512, 512,
                                             dvec, nullptr, nullptr, nullptr);
  k_energy <<<M_ROWS, 256, 0, stream>>>(zdct, energy);
  k3_median<<<BB, 256, 0, stream>>>(energy, ne);
  k3_thr   <<<1, 1024, 0, stream>>>(ne, threshold, thr);

  // --- z1 = idct(gelu(conv1(mask*zdct))) + freq_res ---
  k4_pre   <<<5136, 256, 0, stream>>>(zdct, ne, thr, conv1_w, conv1_b, dvec);
  gemm_nt<1><<<dim3(8,81), 256, 0, stream>>>(zdct, CoT, z1, M_ROWS, 512, 512,
                                             conv1_w, conv1_b, xt, nullptr);

  // --- z2 (patch path), z2_f = conv1(bnD(gelu(dct(z2)))) into zdct buf ---
  k5_z2    <<<M_ROWS, 256, 0, stream>>>(xt, Mp, c2p, z2);
  gemm_nt<2><<<dim3(8,81), 256, 0, stream>>>(z2, Co, zdct, M_ROWS, 512, 512,
                                             Af, Cf, nullptr, dvec);

  // --- convs, gates, z1c, att-dot ---
  k7_fuse  <<<M_ROWS, 256, 0, stream>>>(z1, zdct, z2, z1c, zdpre,
                                        conv2_w, conv2_b, conv3_w, conv3_b,
                                        Af, Cf, dns, Bf, catt);
  k8_att   <<<BB, 256, 0, stream>>>(zdpre, att1, att_dw_b, att_conv_w, att_conv_b,
                                    att_g, att_b, att_m, att_v);
  k8b_zf   <<<5136, 256, 0, stream>>>(z1c, z2, att1, z1);   // zf into z1 buf

  // --- MLP head + linear residual, transposed store ---
  gemm_nt<3><<<dim3(2,81), 256, 0, stream>>>(z1, fc1T, h, M_ROWS, 96, 96,
                                             fc1_b, nullptr, nullptr, nullptr);
  gemm_nt<4><<<dim3(2,81), 256, 0, stream>>>(xt, WeffT, zres, M_ROWS, 96, 96,
                                             cres, nullptr, nullptr, nullptr);
  k9_final <<<dim3(11,BB), 256, 0, stream>>>(h, zres, fc2_w, fc2_b, (float*)d_out);
}

// Round 3
// 792.846 us; speedup vs baseline: 1.1328x; 1.1328x over previous
//
#include <hip/hip_runtime.h>
#include <cmath>

// ---------------------------------------------------------------------------
// Backbone forward (B=32, L=512, D=321, P=16, N=32, dm=256, pred=96), fp32.
// ---------------------------------------------------------------------------

#define BB   32
#define LL   512
#define DD   321
#define PRED 96
#define M_ROWS (BB*DD)          // 10272 rows of length 512

__device__ __forceinline__ float gelu_f(float x){
  return 0.5f*x*(1.0f + erff(x*0.70710678118654752440f));
}
__device__ __forceinline__ float sigmoid_f(float x){
  return 1.0f/(1.0f+expf(-x));
}

// ---------------- workspace layout (floats) --------------------------------
constexpr size_t OFF_CO   = 0;                        // Co[512][512]
constexpr size_t OFF_COT  = OFF_CO   + 512*512;       // CoT[512][512]
constexpr size_t OFF_DVEC = OFF_COT  + 512*512;       // dvec[512]
constexpr size_t OFF_CATT = OFF_DVEC + 512;           // catt[512]
constexpr size_t OFF_FC1T = OFF_CATT + 512;           // fc1T[96][512]
constexpr size_t OFF_WEFFT= OFF_FC1T + 96*512;        // WeffT[96][512]
constexpr size_t OFF_CRES = OFF_WEFFT+ 96*512;        // cres[96] (pad 128)
constexpr size_t OFF_MP   = OFF_CRES + 128;           // M'[32][16][16]
constexpr size_t OFF_C2P  = OFF_MP   + 32*256;        // c2'[32][16]
constexpr size_t OFF_AF   = OFF_C2P  + 512;           // Af[321] pad 384
constexpr size_t OFF_CF   = OFF_AF   + 384;
constexpr size_t OFF_DNS  = OFF_CF   + 384;
constexpr size_t OFF_BF   = OFF_DNS  + 384;
constexpr size_t OFF_EN   = OFF_BF   + 384;           // energy[10272] pad 10368
constexpr size_t OFF_NE   = OFF_EN   + 10368;         // ne[10272]
constexpr size_t OFF_THR  = OFF_NE   + 10368;         // thr scalar (pad 64)
constexpr size_t OFF_ZDP  = OFF_THR  + 64;            // zdpre[10272]
constexpr size_t OFF_ATT1 = OFF_ZDP  + 10368;         // att1[10272]
constexpr size_t OFF_XT   = OFF_ATT1 + 10368;         // xt  [10272][512]
constexpr size_t OFF_ZDCT = OFF_XT   + (size_t)M_ROWS*512; // zdct (reused z2f)
constexpr size_t OFF_Z1   = OFF_ZDCT + (size_t)M_ROWS*512; // z1 (reused zf)
constexpr size_t OFF_Z2   = OFF_Z1   + (size_t)M_ROWS*512;
constexpr size_t OFF_Z1C  = OFF_Z2   + (size_t)M_ROWS*512;
constexpr size_t OFF_H    = OFF_Z1C  + (size_t)M_ROWS*512; // h[10272][96]
constexpr size_t OFF_ZRES = OFF_H    + (size_t)M_ROWS*96;  // zres[10272][96]
constexpr size_t OFF_WPART= OFF_ZRES + (size_t)M_ROWS*96;  // Wpart[4][96][512]
constexpr size_t OFF_PCRES= OFF_WPART+ 4*96*512;           // pcres[128][96]
constexpr size_t WS_FLOATS= OFF_PCRES+ 128*96;

// ---------------- precompute: DCT matrices (row-coalesced both ways) --------
__global__ __launch_bounds__(256)
void k0_dct(float* __restrict__ Co, float* __restrict__ CoT, float* __restrict__ dvec,
            float* __restrict__ catt, const float* __restrict__ attw)
{
  const float PI_F = 3.14159265358979323846f;     // rounds to f32 pi (matches jnp)
  int b = blockIdx.x;                             // row index for both outputs
  // Co row b: Co[b][l] = cos(pi*(2l+1)*b/1024) * ck(b)
  float ckb = (b==0) ? (1.0f/sqrtf(512.0f)) : sqrtf(2.0f/512.0f);
  for (int l=threadIdx.x; l<512; l+=256){
    float a1 = PI_F * (float)(2*l+1);
    float a2 = a1 * (float)b;
    float c  = cosf(a2 * (1.0f/1024.0f)) * ckb;
    Co[b*512+l] = c;
  }
  // CoT row b: CoT[b][k] = Co[k][b] = cos(pi*(2b+1)*k/1024) * ck(k)
  for (int k=threadIdx.x; k<512; k+=256){
    float ckk = (k==0) ? (1.0f/sqrtf(512.0f)) : sqrtf(2.0f/512.0f);
    float a1 = PI_F * (float)(2*b+1);
    float a2 = a1 * (float)k;
    CoT[b*512+k] = cosf(a2 * (1.0f/1024.0f)) * ckk;
  }
  if (threadIdx.x==0) dvec[b] = (b==0) ? 2.0f*sqrtf(512.0f) : sqrtf(2.0f*512.0f);
  if (b==0){
    for (int l=threadIdx.x; l<512; l+=256){
      float sacc=0.f;
      for (int j=0;j<5;j++){
        float ckj = (j==0)?(1.0f/sqrtf(512.0f)):sqrtf(2.0f/512.0f);
        float a1 = PI_F*(float)(2*l+1);
        float a2 = a1*(float)j;
        sacc += cosf(a2 * (1.0f/1024.0f))*ckj*attw[j];
      }
      catt[l]=sacc;
    }
  }
}

// ---------------- precompute: WeffT partials + cres partials ----------------
// Weff[l][pr] = sum_j embed_w[p][j]*lrw[(n*256+j)*96+pr],  l = n*16+p.
// Grid (32 n, 4 kchunk); LDS-staged, 6 FMA per lrw read; K-split partials.
__global__ __launch_bounds__(256)
void kA_weff(const float* __restrict__ ew_g, const float* __restrict__ eb_g,
             const float* __restrict__ lrw,
             float* __restrict__ Wpart, float* __restrict__ pcres)
{
  const int n = blockIdx.x, kb4 = blockIdx.y;     // K-chunk of 64
  __shared__ float ews[16][68];                    // 68: offsets p 4 banks apart
  __shared__ float ebs[64];
  __shared__ float lw[64][96];
  const int tid = threadIdx.x;
  const int jbase = kb4*64;
  for (int i=tid; i<1024; i+=256){
    int p2 = i>>6, j2 = i&63;
    ews[p2][j2] = ew_g[p2*256 + jbase + j2];
  }
  if (tid < 64) ebs[tid] = eb_g[jbase + tid];
  for (int i=tid; i<1536; i+=256){                 // lrw slice [64][96] as float4
    int jj = i/24, c4 = i%24;
    *(float4*)&lw[jj][c4*4] =
      *(const float4*)&lrw[((size_t)(n*256 + jbase + jj))*96 + c4*4];
  }
  __syncthreads();
  const int p = tid>>4, tx = tid&15;
  float acc[6]={0,0,0,0,0,0};
  float accB[6]={0,0,0,0,0,0};
  for (int jj=0; jj<64; jj++){
    float a = ews[p][jj];
    #pragma unroll
    for (int g=0; g<6; g++) acc[g] = fmaf(a, lw[jj][tx+16*g], acc[g]);
    if (p==0){
      float bv = ebs[jj];
      #pragma unroll
      for (int g=0; g<6; g++) accB[g] = fmaf(bv, lw[jj][tx+16*g], accB[g]);
    }
  }
  #pragma unroll
  for (int g=0; g<6; g++){
    int pr = tx + 16*g;
    Wpart[((size_t)kb4*96 + pr)*512 + n*16 + p] = acc[g];
    if (p==0) pcres[(n*4+kb4)*96 + pr] = accB[g];
  }
}

// ---------------- reduce WeffT partials + cres ------------------------------
__global__ __launch_bounds__(256)
void kA_fin(const float* __restrict__ Wpart, const float* __restrict__ pcres,
            const float* __restrict__ lrb,
            float* __restrict__ WeffT, float* __restrict__ cres)
{
  int b = blockIdx.x;
  if (b < 192){
    int i = b*256 + threadIdx.x;                   // over 96*512 = 49152
    WeffT[i] = (Wpart[i] + Wpart[49152+i]) + (Wpart[2*49152+i] + Wpart[3*49152+i]);
  } else {
    int pr = threadIdx.x;
    if (pr < 96){
      float s = lrb[pr];
      for (int nn=0; nn<128; nn++) s += pcres[nn*96+pr];
      cres[pr] = s;
    }
  }
}

// ---------------- fc1T = transpose(fc1_w [512][96]) -------------------------
__global__ __launch_bounds__(256)
void kT_fc1(const float* __restrict__ fc1_w, float* __restrict__ fc1T)
{
  __shared__ float t[32][33];
  int c0 = blockIdx.x*32;   // over 96
  int l0 = blockIdx.y*32;   // over 512
  int tid=threadIdx.x; int j=tid&31, i0=tid>>5;
  for (int ii=0; ii<32; ii+=8){
    int l=l0+i0+ii, c=c0+j;
    t[i0+ii][j] = (c<96)? fc1_w[l*96+c] : 0.f;
  }
  __syncthreads();
  for (int ii=0; ii<32; ii+=8){
    int c=c0+i0+ii, l=l0+j;
    if (c<96) fc1T[(size_t)c*512 + l] = t[j][i0+ii];
  }
}

// ---------------- precompute: patch matrix M' (+BN fold) --------------------
__global__ __launch_bounds__(256)
void k0_depth(const float* __restrict__ embed_w, const float* __restrict__ embed_b,
              const float* __restrict__ drw, const float* __restrict__ drb,
              const float* __restrict__ dcw, const float* __restrict__ dcb,
              const float* __restrict__ png, const float* __restrict__ pnb,
              const float* __restrict__ pnm, const float* __restrict__ pnv,
              float* __restrict__ Mp, float* __restrict__ c2p)
{
  int n = blockIdx.x; int tid = threadIdx.x;
  int q = tid>>4, p = tid&15;
  float acc = 0.f;                       // depth_conv part
  for (int j=0;j<16;j++)  acc = fmaf(embed_w[q*256 + p*16 + j], dcw[n*16+j], acc);
  float wtr = 0.f;                       // time_res part
  for (int j=0;j<256;j++) wtr = fmaf(embed_w[q*256 + j], drw[j*16+p], wtr);
  float sn = png[n]/sqrtf(pnv[n]+1e-5f);
  Mp[n*256 + q*16 + p] = (acc + wtr) * sn;
  if (q==0){
    float c = dcb[n];
    for (int j=0;j<16;j++)  c = fmaf(embed_b[p*16+j], dcw[n*16+j], c);
    float ctr = drb[p];
    for (int j=0;j<256;j++) ctr = fmaf(embed_b[j], drw[j*16+p], ctr);
    c += ctr;
    c2p[n*16+p] = (c - pnm[n])*sn + pnb[n];
  }
}

// ---------------- precompute: per-channel BN/conv1 folds --------------------
__global__ void k0_fold(const float* __restrict__ w1, const float* __restrict__ b1,
                        const float* __restrict__ g,  const float* __restrict__ bbq,
                        const float* __restrict__ mq, const float* __restrict__ vq,
                        float* __restrict__ Af, float* __restrict__ Cf,
                        float* __restrict__ dns, float* __restrict__ Bf)
{
  int d = blockIdx.x*256 + threadIdx.x;
  if (d >= DD) return;
  float s  = g[d]/sqrtf(vq[d]+1e-5f);
  float bf = bbq[d] - mq[d]*s;
  dns[d]=s; Bf[d]=bf; Af[d]=s*w1[d]; Cf[d]=bf*w1[d]+b1[d];
}

// ---------------- transpose x[B,L,D] -> xt[B*D,512] -------------------------
__global__ __launch_bounds__(256)
void k1_transpose(const float* __restrict__ x, float* __restrict__ xt)
{
  int b = blockIdx.z; int l0 = blockIdx.y*32; int d0 = blockIdx.x*32;
  __shared__ float t[32][33];
  int tid=threadIdx.x; int j = tid&31, i0 = tid>>5;
  for (int ii=0; ii<32; ii+=8){
    int l = l0 + i0+ii; int d = d0 + j;
    t[i0+ii][j] = (d<DD) ? x[((size_t)b*512 + l)*DD + d] : 0.f;
  }
  __syncthreads();
  for (int ii=0; ii<32; ii+=8){
    int d = d0 + i0+ii; int l = l0 + j;
    if (d<DD) xt[((size_t)b*DD+d)*512 + l] = t[j][i0+ii];
  }
}

// ---------------- generic NT GEMM: C[r,c] = sum_k A[r,k]*B[c,k] -------------
// OP=0: *=dvec[c], store zdct.       OP=1: + xt*w1+b1 (freq_res), store z1.
// OP=2: gelu(acc*dvec[c])*Af+Cf.     OP=3: gelu(acc+fc1_b[c]) -> h (96 cols).
// OP=4: acc + cres[c] -> zres (96 cols).
template<int OP>
__global__ __launch_bounds__(256)
void gemm_nt(const float* __restrict__ A, const float* __restrict__ B,
             float* __restrict__ C, int M, int Ncols, int ldc,
             const float* __restrict__ p0, const float* __restrict__ p1,
             const float* __restrict__ p2, const float* __restrict__ p3)
{
  __shared__ float As[32][132];   // +4 pad keeps 16B alignment, spreads banks
  __shared__ float Bs[32][68];
  const int tid = threadIdx.x;
  const int tx = tid & 15, ty = tid >> 4;
  const int rb = blockIdx.y * 128, cb = blockIdx.x * 64;

  float acc[8][4];
  #pragma unroll
  for (int i=0;i<8;i++)
    #pragma unroll
    for (int j=0;j<4;j++) acc[i][j]=0.f;

  for (int kb=0; kb<512; kb+=32){
    #pragma unroll
    for (int i=0;i<4;i++){
      int idx = tid + i*256;
      int row = idx >> 3, k4 = (idx & 7)*4;
      float4 v = make_float4(0.f,0.f,0.f,0.f);
      int r = rb + row;
      if (r < M) v = *reinterpret_cast<const float4*>(A + (size_t)r*512 + kb + k4);
      As[k4+0][row]=v.x; As[k4+1][row]=v.y; As[k4+2][row]=v.z; As[k4+3][row]=v.w;
    }
    #pragma unroll
    for (int i=0;i<2;i++){
      int idx = tid + i*256;
      int row = idx >> 3, k4 = (idx & 7)*4;
      float4 v = make_float4(0.f,0.f,0.f,0.f);
      int c = cb + row;
      if (c < Ncols) v = *reinterpret_cast<const float4*>(B + (size_t)c*512 + kb + k4);
      Bs[k4+0][row]=v.x; Bs[k4+1][row]=v.y; Bs[k4+2][row]=v.z; Bs[k4+3][row]=v.w;
    }
    __syncthreads();
    #pragma unroll
    for (int kk=0; kk<32; kk++){
      const float4 a0 = *reinterpret_cast<const float4*>(&As[kk][ty*8]);
      const float4 a1 = *reinterpret_cast<const float4*>(&As[kk][ty*8+4]);
      const float4 b0 = *reinterpret_cast<const float4*>(&Bs[kk][tx*4]);
      float av[8]={a0.x,a0.y,a0.z,a0.w,a1.x,a1.y,a1.z,a1.w};
      float bv[4]={b0.x,b0.y,b0.z,b0.w};
      #pragma unroll
      for (int i=0;i<8;i++)
        #pragma unroll
        for (int j=0;j<4;j++) acc[i][j]=fmaf(av[i],bv[j],acc[i][j]);
    }
    __syncthreads();
  }

  #pragma unroll
  for (int i=0;i<8;i++){
    const int r = rb + ty*8 + i;
    const bool rok = (r < M);
    if constexpr (OP==0){
      if (rok){
        #pragma unroll
        for (int j=0;j<4;j++){
          int c = cb + tx*4 + j;
          C[(size_t)r*ldc + c] = acc[i][j]*p0[c];          // p0 = dvec
        }
      }
    } else if constexpr (OP==1){
      if (rok){
        int d = r % DD;
        float w = p0[d], bo = p1[d];                        // conv1_w / conv1_b
        #pragma unroll
        for (int j=0;j<4;j++){
          int c = cb + tx*4 + j;
          C[(size_t)r*ldc + c] = acc[i][j] + p2[(size_t)r*512 + c]*w + bo;  // p2 = xt
        }
      }
    } else if constexpr (OP==2){
      if (rok){
        int d = r % DD;
        float w = p0[d], bo = p1[d];                        // Af / Cf
        #pragma unroll
        for (int j=0;j<4;j++){
          int c = cb + tx*4 + j;
          float t = acc[i][j]*p3[c];                        // p3 = dvec
          C[(size_t)r*ldc + c] = gelu_f(t)*w + bo;
        }
      }
    } else if constexpr (OP==3){
      if (rok){
        #pragma unroll
        for (int j=0;j<4;j++){
          int c = cb + tx*4 + j;
          if (c < Ncols) C[(size_t)r*ldc + c] = gelu_f(acc[i][j] + p0[c]); // p0=fc1_b
        }
      }
    } else {   // OP==4
      if (rok){
        #pragma unroll
        for (int j=0;j<4;j++){
          int c = cb + tx*4 + j;
          if (c < Ncols) C[(size_t)r*ldc + c] = acc[i][j] + p0[c];        // p0=cres
        }
      }
    }
  }
}

// ---------------- energy per row (deterministic) ----------------------------
__global__ __launch_bounds__(256)
void k_energy(const float* __restrict__ zdct, float* __restrict__ energy)
{
  int r=blockIdx.x, tid=threadIdx.x;
  __shared__ float rbuf[256];
  float acc=0.f;
  for (int k=tid;k<512;k+=256){ float v=zdct[(size_t)r*512+k]; acc=fmaf(v,v,acc); }
  rbuf[tid]=acc; __syncthreads();
  for (int st=128;st>0;st>>=1){ if(tid<st) rbuf[tid]+=rbuf[tid+st]; __syncthreads(); }
  if (tid==0) energy[r]=rbuf[0];
}

// ---------------- median over D per batch, ne = e/(med+1e-6) ----------------
__global__ __launch_bounds__(256)
void k3_median(const float* __restrict__ energy, float* __restrict__ ne)
{
  int b = blockIdx.x, tid=threadIdx.x;
  __shared__ float e[DD];
  __shared__ float medv;
  for (int i=tid;i<DD;i+=256) e[i]=energy[b*DD+i];
  __syncthreads();
  for (int i=tid;i<DD;i+=256){
    float v=e[i]; int lt=0, eq=0;
    for (int j=0;j<DD;j++){ float u=e[j]; lt += (u<v); eq += (u==v); }
    if (lt<=160 && 160<lt+eq) medv=v;      // 0-based rank 160 of 321
  }
  __syncthreads();
  float den = medv + 1e-6f;
  for (int i=tid;i<DD;i+=256) ne[b*DD+i] = e[i]/den;
}

// ---------------- quantile via radix select (2 ranks + lerp) ----------------
__global__ __launch_bounds__(1024)
void k3_thr(const float* __restrict__ ne, const float* __restrict__ thrin,
            float* __restrict__ out)
{
  __shared__ int hist[256];
  __shared__ unsigned sPrefix; __shared__ int sRank;
  int tid = threadIdx.x;
  float q = fminf(fmaxf(thrin[0],0.f),1.f);
  float pos = q * (float)(M_ROWS-1);
  int lo = (int)floorf(pos); int hi = (int)ceilf(pos);
  float frac = pos - floorf(pos);
  float vals[2];
  for (int s=0;s<2;s++){
    int rank = s ? hi : lo;
    unsigned prefix=0, pmask=0;
    for (int pass=0; pass<4; pass++){
      int shift = 24 - 8*pass;
      if (tid<256) hist[tid]=0;
      __syncthreads();
      for (int i=tid;i<M_ROWS;i+=1024){
        unsigned u = __float_as_uint(ne[i]);      // ne >= 0 -> bits order = value order
        if ((u & pmask)==prefix) atomicAdd(&hist[(u>>shift)&255u],1);
      }
      __syncthreads();
      if (tid==0){
        int cum=0;
        for (int bkt=0;bkt<256;bkt++){
          int c=hist[bkt];
          if (cum + c > rank){ sPrefix = prefix | ((unsigned)bkt<<(unsigned)shift); sRank = rank - cum; break; }
          cum += c;
        }
      }
      __syncthreads();
      prefix = sPrefix; rank = sRank; pmask |= (0xFFu<<(unsigned)shift);
      __syncthreads();
    }
    vals[s] = __uint_as_float(prefix);
  }
  if (tid==0) out[0] = vals[0]*(1.0f-frac) + vals[1]*frac;
}

// ---------------- in-place transform of zdct before IDCT --------------------
__global__ void k4_pre(float* __restrict__ zdct, const float* __restrict__ ne,
                       const float* __restrict__ thr, const float* __restrict__ w1,
                       const float* __restrict__ b1, const float* __restrict__ dvec)
{
  size_t idx = (size_t)blockIdx.x*256 + threadIdx.x;   // over 10272*128 float4
  int r = (int)(idx>>7);
  int k0 = ((int)idx & 127)*4;
  float m  = (ne[r] > thr[0]) ? 1.f : 0.f;
  int d = r % DD;
  float w = w1[d]*m, bo = b1[d];
  float4 v = ((float4*)zdct)[idx];
  v.x = gelu_f(fmaf(v.x,w,bo))/dvec[k0+0];
  v.y = gelu_f(fmaf(v.y,w,bo))/dvec[k0+1];
  v.z = gelu_f(fmaf(v.z,w,bo))/dvec[k0+2];
  v.w = gelu_f(fmaf(v.w,w,bo))/dvec[k0+3];
  ((float4*)zdct)[idx]=v;
}

// ---------------- z2: per-patch 16x16 matmul + gelu -------------------------
__global__ __launch_bounds__(256)
void k5_z2(const float* __restrict__ xt, const float* __restrict__ Mp,
           const float* __restrict__ c2p, float* __restrict__ z2)
{
  int r = blockIdx.x, tid=threadIdx.x;
  __shared__ float row[512];
  for (int i=tid;i<512;i+=256) row[i]=xt[(size_t)r*512+i];
  __syncthreads();
  for (int idx=tid; idx<512; idx+=256){
    int n = idx>>4, p = idx&15;
    float acc = c2p[idx];
    const float* Mn = Mp + n*256 + p;
    #pragma unroll
    for (int qq=0;qq<16;qq++) acc = fmaf(row[n*16+qq], Mn[qq*16], acc);
    z2[(size_t)r*512+idx] = gelu_f(acc);
  }
}

// ---------------- fused convs / gates / z1c / att-dot -----------------------
__global__ __launch_bounds__(256)
void k7_fuse(const float* __restrict__ z1, const float* __restrict__ z2f,
             const float* __restrict__ z2, float* __restrict__ z1c,
             float* __restrict__ zdpre,
             const float* __restrict__ c2w, const float* __restrict__ c2b,
             const float* __restrict__ c3w, const float* __restrict__ c3b,
             const float* __restrict__ Af,  const float* __restrict__ Cf,
             const float* __restrict__ dns, const float* __restrict__ Bf,
             const float* __restrict__ catt)
{
  int r = blockIdx.x, tid=threadIdx.x;
  int d = r % DD;
  __shared__ float zrow[518];
  __shared__ float rbuf[256];
  for (int i=tid;i<518;i+=256){
    int l = i-3;
    zrow[i] = (l>=0 && l<512) ? z1[(size_t)r*512+l] : 0.f;
  }
  __syncthreads();
  float w2[5], w3[7];
  #pragma unroll
  for (int t=0;t<5;t++) w2[t]=c2w[d*5+t];
  #pragma unroll
  for (int t=0;t<7;t++) w3[t]=c3w[d*7+t];
  const float cb2=c2b[d], cb3=c3b[d];
  const float af=Af[d], cf=Cf[d], s=dns[d], bf=Bf[d];
  float dotacc=0.f;
  for (int l=tid;l<512;l+=256){
    float c5=cb2;
    #pragma unroll
    for (int t=0;t<5;t++) c5 = fmaf(zrow[l+t+1], w2[t], c5);   // pad-2 conv k=5
    float zr  = sigmoid_f(fmaf(gelu_f(c5),af,cf));
    float zgv = gelu_f(z2f[(size_t)r*512+l]*zr);
    float c7=cb3;
    #pragma unroll
    for (int t=0;t<7;t++) c7 = fmaf(zrow[l+t], w3[t], c7);     // pad-3 conv k=7
    float z1b = gelu_f(fmaf(c7,s,bf));
    float v = fmaf(zgv,s,bf) + z1b;                            // z1c = bnD(zg)+z1b
    z1c[(size_t)r*512+l]=v;
    dotacc = fmaf(v*z2[(size_t)r*512+l], catt[l], dotacc);
  }
  rbuf[tid]=dotacc; __syncthreads();
  for (int st=128;st>0;st>>=1){ if(tid<st) rbuf[tid]+=rbuf[tid+st]; __syncthreads(); }
  if (tid==0) zdpre[r]=rbuf[0];
}

// ---------------- attention scalar path + softmax over D --------------------
__global__ __launch_bounds__(256)
void k8_att(const float* __restrict__ zdpre, float* __restrict__ att1,
            const float* __restrict__ adwb, const float* __restrict__ acw,
            const float* __restrict__ acb,  const float* __restrict__ ag,
            const float* __restrict__ ab,   const float* __restrict__ am,
            const float* __restrict__ av)
{
  int b=blockIdx.x, t=threadIdx.x;
  __shared__ float sred[256];
  float vloc[2];
  float mx=-INFINITY;
  float sA = ag[0]/sqrtf(av[0]+1e-5f);
  #pragma unroll
  for (int ii=0;ii<2;ii++){
    int d=t+ii*256;
    float v=-INFINITY;
    if (d<DD){
      float zd = zdpre[b*DD+d] + adwb[0];
      zd = gelu_f(zd);
      zd = (zd-am[0])*sA + ab[0];
      zd = zd*acw[0] + acb[0];
      v=zd;
    }
    vloc[ii]=v; mx=fmaxf(mx,v);
  }
  sred[t]=mx; __syncthreads();
  for (int st=128;st>0;st>>=1){ if (t<st) sred[t]=fmaxf(sred[t],sred[t+st]); __syncthreads(); }
  float m=sred[0]; __syncthreads();
  float e0 = (t<DD)     ? expf(vloc[0]-m) : 0.f;
  float e1 = (t+256<DD) ? expf(vloc[1]-m) : 0.f;
  sred[t]=e0+e1; __syncthreads();
  for (int st=128;st>0;st>>=1){ if (t<st) sred[t]+=sred[t+st]; __syncthreads(); }
  float sum=sred[0];
  if (t<DD)     att1[b*DD+t]     = e0/sum;
  if (t+256<DD) att1[b*DD+t+256] = e1/sum;
}

// ---------------- zf = z1c*att + z2*(1-att) ---------------------------------
__global__ void k8b_zf(const float* __restrict__ z1c, const float* __restrict__ z2,
                       const float* __restrict__ att1, float* __restrict__ zf)
{
  size_t idx = (size_t)blockIdx.x*256 + threadIdx.x;   // over 10272*128 float4
  int r = (int)(idx>>7);
  float a = att1[r];
  float4 v1 = ((const float4*)z1c)[idx];
  float4 v2 = ((const float4*)z2)[idx];
  float4 o;
  o.x = v1.x*a + v2.x*(1.f-a);
  o.y = v1.y*a + v2.y*(1.f-a);
  o.z = v1.z*a + v2.z*(1.f-a);
  o.w = v1.w*a + v2.w*(1.f-a);
  ((float4*)zf)[idx]=o;
}

// ---------------- final: out = h@fc2 + fc2_b + zres, transposed store -------
__global__ __launch_bounds__(256)
void k9_final(const float* __restrict__ h, const float* __restrict__ zres,
              const float* __restrict__ fc2_w, const float* __restrict__ fc2_b,
              float* __restrict__ outF)
{
  int b = blockIdx.y; int d0 = blockIdx.x*32;
  __shared__ float f2[96*96];
  __shared__ float hs[32][97];
  __shared__ float zs[32][97];
  int tid=threadIdx.x;
  for (int i=tid;i<96*96;i+=256) f2[i]=fc2_w[i];
  for (int i=tid;i<32*96;i+=256){
    int dl = i/96, p = i%96; int d = d0+dl;
    float hv=0.f, zv=0.f;
    if (d<DD){ hv = h[((size_t)b*DD+d)*96+p]; zv = zres[((size_t)b*DD+d)*96+p]; }
    hs[dl][p]=hv; zs[dl][p]=zv;
  }
  __syncthreads();
  int tx = tid & 31, ty = tid >> 5;       // tx: d_local, ty: 0..7
  int d = d0+tx;
  float acc[12];
  #pragma unroll
  for (int kc=0;kc<12;kc++) acc[kc]=0.f;
  for (int p=0;p<96;p++){
    float hv = hs[tx][p];
    #pragma unroll
    for (int kc=0;kc<12;kc++) acc[kc] = fmaf(hv, f2[p*96 + ty + kc*8], acc[kc]);
  }
  if (d<DD){
    #pragma unroll
    for (int kc=0;kc<12;kc++){
      int c = ty + kc*8;
      outF[((size_t)b*96 + c)*DD + d] = acc[kc] + fc2_b[c] + zs[tx][c];
    }
  }
}

// ---------------------------------------------------------------------------
extern "C" void kernel_launch(void* const* d_in, const int* in_sizes, int n_in,
                              void* d_out, int out_size, void* d_ws, size_t ws_size,
                              hipStream_t stream)
{
  (void)in_sizes; (void)n_in; (void)out_size; (void)ws_size;
  const float* x        =(const float*)d_in[0];
  const float* conv1_w  =(const float*)d_in[1];
  const float* conv1_b  =(const float*)d_in[2];
  const float* conv2_w  =(const float*)d_in[3];
  const float* conv2_b  =(const float*)d_in[4];
  const float* conv3_w  =(const float*)d_in[5];
  const float* conv3_b  =(const float*)d_in[6];
  const float* dn_g     =(const float*)d_in[7];
  const float* dn_b     =(const float*)d_in[8];
  const float* dn_m     =(const float*)d_in[9];
  const float* dn_v     =(const float*)d_in[10];
  const float* pn_g     =(const float*)d_in[11];
  const float* pn_b     =(const float*)d_in[12];
  const float* pn_m     =(const float*)d_in[13];
  const float* pn_v     =(const float*)d_in[14];
  const float* embed_w  =(const float*)d_in[15];
  const float* embed_b  =(const float*)d_in[16];
  const float* lin_res_w=(const float*)d_in[17];
  const float* lin_res_b=(const float*)d_in[18];
  const float* depth_res_w=(const float*)d_in[19];
  const float* depth_res_b=(const float*)d_in[20];
  const float* depth_conv_w=(const float*)d_in[21];
  const float* depth_conv_b=(const float*)d_in[22];
  const float* threshold=(const float*)d_in[23];
  const float* att_dw_w =(const float*)d_in[24];
  const float* att_dw_b =(const float*)d_in[25];
  const float* att_conv_w=(const float*)d_in[26];
  const float* att_conv_b=(const float*)d_in[27];
  const float* att_g    =(const float*)d_in[28];
  const float* att_b    =(const float*)d_in[29];
  const float* att_m    =(const float*)d_in[30];
  const float* att_v    =(const float*)d_in[31];
  const float* fc1_w    =(const float*)d_in[32];
  const float* fc1_b    =(const float*)d_in[33];
  const float* fc2_w    =(const float*)d_in[34];
  const float* fc2_b    =(const float*)d_in[35];

  float* ws   = (float*)d_ws;
  float* Co   = ws + OFF_CO;
  float* CoT  = ws + OFF_COT;
  float* dvec = ws + OFF_DVEC;
  float* catt = ws + OFF_CATT;
  float* fc1T = ws + OFF_FC1T;
  float* WeffT= ws + OFF_WEFFT;
  float* cres = ws + OFF_CRES;
  float* Mp   = ws + OFF_MP;
  float* c2p  = ws + OFF_C2P;
  float* Af   = ws + OFF_AF;
  float* Cf   = ws + OFF_CF;
  float* dns  = ws + OFF_DNS;
  float* Bf   = ws + OFF_BF;
  float* energy=ws + OFF_EN;
  float* ne   = ws + OFF_NE;
  float* thr  = ws + OFF_THR;
  float* zdpre= ws + OFF_ZDP;
  float* att1 = ws + OFF_ATT1;
  float* xt   = ws + OFF_XT;
  float* zdct = ws + OFF_ZDCT;   // later reused as z2f
  float* z1   = ws + OFF_Z1;     // later reused as zf
  float* z2   = ws + OFF_Z2;
  float* z1c  = ws + OFF_Z1C;
  float* h    = ws + OFF_H;
  float* zres = ws + OFF_ZRES;
  float* Wpart= ws + OFF_WPART;
  float* pcres= ws + OFF_PCRES;

  // --- precompute ---
  k0_dct  <<<512, 256, 0, stream>>>(Co, CoT, dvec, catt, att_dw_w);
  kA_weff <<<dim3(32,4), 256, 0, stream>>>(embed_w, embed_b, lin_res_w, Wpart, pcres);
  kA_fin  <<<193, 256, 0, stream>>>(Wpart, pcres, lin_res_b, WeffT, cres);
  kT_fc1  <<<dim3(3,16), 256, 0, stream>>>(fc1_w, fc1T);
  k0_depth<<<32, 256, 0, stream>>>(embed_w, embed_b, depth_res_w, depth_res_b,
                                   depth_conv_w, depth_conv_b, pn_g, pn_b, pn_m, pn_v,
                                   Mp, c2p);
  k0_fold <<<2, 256, 0, stream>>>(conv1_w, conv1_b, dn_g, dn_b, dn_m, dn_v,
                                  Af, Cf, dns, Bf);

  // --- transpose, DCT(x), mask stats ---
  k1_transpose<<<dim3(11,16,BB), 256, 0, stream>>>(x, xt);
  gemm_nt<0><<<dim3(8,81), 256, 0, stream>>>(xt, Co, zdct, M_ROWS, 512, 512,
                                             dvec, nullptr, nullptr, nullptr);
  k_energy <<<M_ROWS, 256, 0, stream>>>(zdct, energy);
  k3_median<<<BB, 256, 0, stream>>>(energy, ne);
  k3_thr   <<<1, 1024, 0, stream>>>(ne, threshold, thr);

  // --- z1 = idct(gelu(conv1(mask*zdct))) + freq_res ---
  k4_pre   <<<5136, 256, 0, stream>>>(zdct, ne, thr, conv1_w, conv1_b, dvec);
  gemm_nt<1><<<dim3(8,81), 256, 0, stream>>>(zdct, CoT, z1, M_ROWS, 512, 512,
                                             conv1_w, conv1_b, xt, nullptr);

  // --- z2 (patch path), z2_f = conv1(bnD(gelu(dct(z2)))) into zdct buf ---
  k5_z2    <<<M_ROWS, 256, 0, stream>>>(xt, Mp, c2p, z2);
  gemm_nt<2><<<dim3(8,81), 256, 0, stream>>>(z2, Co, zdct, M_ROWS, 512, 512,
                                             Af, Cf, nullptr, dvec);

  // --- convs, gates, z1c, att-dot ---
  k7_fuse  <<<M_ROWS, 256, 0, stream>>>(z1, zdct, z2, z1c, zdpre,
                                        conv2_w, conv2_b, conv3_w, conv3_b,
                                        Af, Cf, dns, Bf, catt);
  k8_att   <<<BB, 256, 0, stream>>>(zdpre, att1, att_dw_b, att_conv_w, att_conv_b,
                                    att_g, att_b, att_m, att_v);
  k8b_zf   <<<5136, 256, 0, stream>>>(z1c, z2, att1, z1);   // zf into z1 buf

  // --- MLP head + linear residual, transposed store ---
  gemm_nt<3><<<dim3(2,81), 256, 0, stream>>>(z1, fc1T, h, M_ROWS, 96, 96,
                                             fc1_b, nullptr, nullptr, nullptr);
  gemm_nt<4><<<dim3(2,81), 256, 0, stream>>>(xt, WeffT, zres, M_ROWS, 96, 96,
                                             cres, nullptr, nullptr, nullptr);
  k9_final <<<dim3(11,BB), 256, 0, stream>>>(h, zres, fc2_w, fc2_b, (float*)d_out);
}

// Round 4
// 767.001 us; speedup vs baseline: 1.1709x; 1.0337x over previous
//
#include <hip/hip_runtime.h>
#include <cmath>

// ---------------------------------------------------------------------------
// Backbone forward (B=32, L=512, D=321, P=16, N=32, dm=256, pred=96), fp32.
// Round 4: even/odd DCT factorization halves the FLOPs of the 3 big GEMMs.
// ---------------------------------------------------------------------------

#define BB   32
#define LL   512
#define DD   321
#define PRED 96
#define M_ROWS (BB*DD)          // 10272 rows of length 512

__device__ __forceinline__ float gelu_f(float x){
  return 0.5f*x*(1.0f + erff(x*0.70710678118654752440f));
}
__device__ __forceinline__ float sigmoid_f(float x){
  return 1.0f/(1.0f+expf(-x));
}

// ---------------- workspace layout (floats) --------------------------------
constexpr size_t OFF_COE  = 0;                        // CoE [256][256]
constexpr size_t OFF_COO  = OFF_COE  + 256*256;       // CoO [256][256]
constexpr size_t OFF_COET = OFF_COO  + 256*256;       // CoET[256][256]
constexpr size_t OFF_COOT = OFF_COET + 256*256;       // CoOT[256][256]
constexpr size_t OFF_DVEC = OFF_COOT + 256*256;       // dvec[512]
constexpr size_t OFF_CATT = OFF_DVEC + 512;           // catt[512]
constexpr size_t OFF_FC1T = OFF_CATT + 512;           // fc1T[96][512]
constexpr size_t OFF_WEFFT= OFF_FC1T + 96*512;        // WeffT[96][512]
constexpr size_t OFF_CRES = OFF_WEFFT+ 96*512;        // cres[96] (pad 128)
constexpr size_t OFF_MP   = OFF_CRES + 128;           // M'[32][16][16]
constexpr size_t OFF_C2P  = OFF_MP   + 32*256;        // c2'[32][16]
constexpr size_t OFF_AF   = OFF_C2P  + 512;           // Af[321] pad 384
constexpr size_t OFF_CF   = OFF_AF   + 384;
constexpr size_t OFF_DNS  = OFF_CF   + 384;
constexpr size_t OFF_BF   = OFF_DNS  + 384;
constexpr size_t OFF_EN   = OFF_BF   + 384;           // energy[10272] pad 10368
constexpr size_t OFF_NE   = OFF_EN   + 10368;         // ne[10272]
constexpr size_t OFF_THR  = OFF_NE   + 10368;         // thr scalar (pad 64)
constexpr size_t OFF_ZDP  = OFF_THR  + 64;            // zdpre[10272]
constexpr size_t OFF_ATT1 = OFF_ZDP  + 10368;         // att1[10272]
constexpr size_t OFF_XT   = OFF_ATT1 + 10368;         // xt  [10272][512]
constexpr size_t OFF_ZDCT = OFF_XT   + (size_t)M_ROWS*512; // zdct (reused z2f)
constexpr size_t OFF_Z1   = OFF_ZDCT + (size_t)M_ROWS*512; // z1 (reused zf)
constexpr size_t OFF_Z2   = OFF_Z1   + (size_t)M_ROWS*512;
constexpr size_t OFF_Z1C  = OFF_Z2   + (size_t)M_ROWS*512;
constexpr size_t OFF_H    = OFF_Z1C  + (size_t)M_ROWS*512; // h[10272][96]
constexpr size_t OFF_ZRES = OFF_H    + (size_t)M_ROWS*96;  // zres[10272][96]
constexpr size_t OFF_WPART= OFF_ZRES + (size_t)M_ROWS*96;  // Wpart[4][96][512]
constexpr size_t OFF_PCRES= OFF_WPART+ 4*96*512;           // pcres[128][96]
constexpr size_t WS_FLOATS= OFF_PCRES+ 128*96;

// ---------------- precompute: even/odd DCT matrices -------------------------
// CoE [c][l]  = Co[2c  ][l]  (DCT even rows, B for gemm_dual<0/2> accE)
// CoO [c][l]  = Co[2c+1][l]  (DCT odd rows,  accO)
// CoET[l][k'] = Co[2k' ][l]  (IDCT even part, B for gemm_dual<1> accE)
// CoOT[l][k'] = Co[2k'+1][l] (IDCT odd part,  accO)
__global__ __launch_bounds__(256)
void k0_dctF(float* __restrict__ CoE, float* __restrict__ CoO,
             float* __restrict__ CoET, float* __restrict__ CoOT,
             float* __restrict__ dvec, float* __restrict__ catt,
             const float* __restrict__ attw)
{
  const float PI_F = 3.14159265358979323846f;
  const float ck0 = 1.0f/sqrtf(512.0f), ckn = sqrtf(2.0f/512.0f);
  int c = blockIdx.x;                 // 0..255
  int t = threadIdx.x;                // 0..255
  {
    // CoE/CoO row c, col l=t
    float a1 = PI_F * (float)(2*t+1);
    float ckE = (c==0) ? ck0 : ckn;
    float aE = a1 * (float)(2*c);
    float aO = a1 * (float)(2*c+1);
    CoE[c*256+t] = cosf(aE * (1.0f/1024.0f)) * ckE;
    CoO[c*256+t] = cosf(aO * (1.0f/1024.0f)) * ckn;
  }
  {
    // CoET/CoOT row l=c, col k'=t
    float a1 = PI_F * (float)(2*c+1);
    float ckE = (t==0) ? ck0 : ckn;
    float aE = a1 * (float)(2*t);
    float aO = a1 * (float)(2*t+1);
    CoET[c*256+t] = cosf(aE * (1.0f/1024.0f)) * ckE;
    CoOT[c*256+t] = cosf(aO * (1.0f/1024.0f)) * ckn;
  }
  if (t==0){
    dvec[2*c]   = (c==0) ? 2.0f*sqrtf(512.0f) : sqrtf(2.0f*512.0f);
    dvec[2*c+1] = sqrtf(2.0f*512.0f);
  }
  if (c==0){
    for (int l=t; l<512; l+=256){
      float sacc=0.f;
      for (int j=0;j<5;j++){
        float ckj = (j==0)? ck0 : ckn;
        float a1 = PI_F*(float)(2*l+1);
        float a2 = a1*(float)j;
        sacc += cosf(a2 * (1.0f/1024.0f))*ckj*attw[j];
      }
      catt[l]=sacc;
    }
  }
}

// ---------------- precompute: WeffT partials + cres partials ----------------
__global__ __launch_bounds__(256)
void kA_weff(const float* __restrict__ ew_g, const float* __restrict__ eb_g,
             const float* __restrict__ lrw,
             float* __restrict__ Wpart, float* __restrict__ pcres)
{
  const int n = blockIdx.x, kb4 = blockIdx.y;     // K-chunk of 64
  __shared__ float ews[16][68];
  __shared__ float ebs[64];
  __shared__ float lw[64][96];
  const int tid = threadIdx.x;
  const int jbase = kb4*64;
  for (int i=tid; i<1024; i+=256){
    int p2 = i>>6, j2 = i&63;
    ews[p2][j2] = ew_g[p2*256 + jbase + j2];
  }
  if (tid < 64) ebs[tid] = eb_g[jbase + tid];
  for (int i=tid; i<1536; i+=256){                 // lrw slice [64][96] as float4
    int jj = i/24, c4 = i%24;
    *(float4*)&lw[jj][c4*4] =
      *(const float4*)&lrw[((size_t)(n*256 + jbase + jj))*96 + c4*4];
  }
  __syncthreads();
  const int p = tid>>4, tx = tid&15;
  float acc[6]={0,0,0,0,0,0};
  float accB[6]={0,0,0,0,0,0};
  for (int jj=0; jj<64; jj++){
    float a = ews[p][jj];
    #pragma unroll
    for (int g=0; g<6; g++) acc[g] = fmaf(a, lw[jj][tx+16*g], acc[g]);
    if (p==0){
      float bv = ebs[jj];
      #pragma unroll
      for (int g=0; g<6; g++) accB[g] = fmaf(bv, lw[jj][tx+16*g], accB[g]);
    }
  }
  #pragma unroll
  for (int g=0; g<6; g++){
    int pr = tx + 16*g;
    Wpart[((size_t)kb4*96 + pr)*512 + n*16 + p] = acc[g];
    if (p==0) pcres[(n*4+kb4)*96 + pr] = accB[g];
  }
}

// ---------------- reduce WeffT partials + cres ------------------------------
__global__ __launch_bounds__(256)
void kA_fin(const float* __restrict__ Wpart, const float* __restrict__ pcres,
            const float* __restrict__ lrb,
            float* __restrict__ WeffT, float* __restrict__ cres)
{
  int b = blockIdx.x;
  if (b < 192){
    int i = b*256 + threadIdx.x;                   // over 96*512 = 49152
    WeffT[i] = (Wpart[i] + Wpart[49152+i]) + (Wpart[2*49152+i] + Wpart[3*49152+i]);
  } else {
    int pr = threadIdx.x;
    if (pr < 96){
      float s = lrb[pr];
      for (int nn=0; nn<128; nn++) s += pcres[nn*96+pr];
      cres[pr] = s;
    }
  }
}

// ---------------- fc1T = transpose(fc1_w [512][96]) -------------------------
__global__ __launch_bounds__(256)
void kT_fc1(const float* __restrict__ fc1_w, float* __restrict__ fc1T)
{
  __shared__ float t[32][33];
  int c0 = blockIdx.x*32;   // over 96
  int l0 = blockIdx.y*32;   // over 512
  int tid=threadIdx.x; int j=tid&31, i0=tid>>5;
  for (int ii=0; ii<32; ii+=8){
    int l=l0+i0+ii, c=c0+j;
    t[i0+ii][j] = (c<96)? fc1_w[l*96+c] : 0.f;
  }
  __syncthreads();
  for (int ii=0; ii<32; ii+=8){
    int c=c0+i0+ii, l=l0+j;
    if (c<96) fc1T[(size_t)c*512 + l] = t[j][i0+ii];
  }
}

// ---------------- precompute: patch matrix M' (+BN fold) --------------------
__global__ __launch_bounds__(256)
void k0_depth(const float* __restrict__ embed_w, const float* __restrict__ embed_b,
              const float* __restrict__ drw, const float* __restrict__ drb,
              const float* __restrict__ dcw, const float* __restrict__ dcb,
              const float* __restrict__ png, const float* __restrict__ pnb,
              const float* __restrict__ pnm, const float* __restrict__ pnv,
              float* __restrict__ Mp, float* __restrict__ c2p)
{
  int n = blockIdx.x; int tid = threadIdx.x;
  int q = tid>>4, p = tid&15;
  float acc = 0.f;                       // depth_conv part
  for (int j=0;j<16;j++)  acc = fmaf(embed_w[q*256 + p*16 + j], dcw[n*16+j], acc);
  float wtr = 0.f;                       // time_res part
  for (int j=0;j<256;j++) wtr = fmaf(embed_w[q*256 + j], drw[j*16+p], wtr);
  float sn = png[n]/sqrtf(pnv[n]+1e-5f);
  Mp[n*256 + q*16 + p] = (acc + wtr) * sn;
  if (q==0){
    float c = dcb[n];
    for (int j=0;j<16;j++)  c = fmaf(embed_b[p*16+j], dcw[n*16+j], c);
    float ctr = drb[p];
    for (int j=0;j<256;j++) ctr = fmaf(embed_b[j], drw[j*16+p], ctr);
    c += ctr;
    c2p[n*16+p] = (c - pnm[n])*sn + pnb[n];
  }
}

// ---------------- precompute: per-channel BN/conv1 folds --------------------
__global__ void k0_fold(const float* __restrict__ w1, const float* __restrict__ b1,
                        const float* __restrict__ g,  const float* __restrict__ bbq,
                        const float* __restrict__ mq, const float* __restrict__ vq,
                        float* __restrict__ Af, float* __restrict__ Cf,
                        float* __restrict__ dns, float* __restrict__ Bf)
{
  int d = blockIdx.x*256 + threadIdx.x;
  if (d >= DD) return;
  float s  = g[d]/sqrtf(vq[d]+1e-5f);
  float bf = bbq[d] - mq[d]*s;
  dns[d]=s; Bf[d]=bf; Af[d]=s*w1[d]; Cf[d]=bf*w1[d]+b1[d];
}

// ---------------- transpose x[B,L,D] -> xt[B*D,512] -------------------------
__global__ __launch_bounds__(256)
void k1_transpose(const float* __restrict__ x, float* __restrict__ xt)
{
  int b = blockIdx.z; int l0 = blockIdx.y*32; int d0 = blockIdx.x*32;
  __shared__ float t[32][33];
  int tid=threadIdx.x; int j = tid&31, i0 = tid>>5;
  for (int ii=0; ii<32; ii+=8){
    int l = l0 + i0+ii; int d = d0 + j;
    t[i0+ii][j] = (d<DD) ? x[((size_t)b*512 + l)*DD + d] : 0.f;
  }
  __syncthreads();
  for (int ii=0; ii<32; ii+=8){
    int d = d0 + i0+ii; int l = l0 + j;
    if (d<DD) xt[((size_t)b*DD+d)*512 + l] = t[j][i0+ii];
  }
}

// ---------------- dual even/odd GEMM for DCT/IDCT (K'=256) ------------------
// OP=0 (DCT): A row r holds x[0..512); staging folds u=x[l]+x[511-l] -> Ae,
//   v=x[l]-x[511-l] -> Ao.  C[r][2c] = accE*dvec, C[r][2c+1] = accO*dvec.
// OP=2 (DCT of z2): same staging; C = gelu(acc*dvec)*Af[d] + Cf[d].
// OP=1 (IDCT): A row holds z[0..512) natural; staging deinterleaves even k'
//   -> Ae, odd k' -> Ao.  C[r][l] = accE+accO + fr(l);
//   C[r][511-l] = accE-accO + fr(511-l),  fr = xt*conv1_w + conv1_b.
template<int OP>
__global__ __launch_bounds__(256)
void gemm_dual(const float* __restrict__ A, const float* __restrict__ BE,
               const float* __restrict__ BO, float* __restrict__ C, int M,
               const float* __restrict__ p0, const float* __restrict__ p1,
               const float* __restrict__ p2, const float* __restrict__ p3)
{
  __shared__ float Ae[32][132];
  __shared__ float Ao[32][132];
  __shared__ float Be[32][68];
  __shared__ float Bo[32][68];
  const int tid = threadIdx.x;
  const int tx = tid & 15, ty = tid >> 4;
  const int rb = blockIdx.y * 128, cb = blockIdx.x * 64;   // cb: dual-col base

  float accE[8][4], accO[8][4];
  #pragma unroll
  for (int i=0;i<8;i++)
    #pragma unroll
    for (int j=0;j<4;j++){ accE[i][j]=0.f; accO[i][j]=0.f; }

  for (int kb=0; kb<256; kb+=32){
    if constexpr (OP==0 || OP==2){
      #pragma unroll
      for (int i=0;i<4;i++){
        int idx = tid + i*256;              // 1024: 128 rows x 8 float4
        int row = idx >> 3, k4 = (idx & 7)*4;
        int r = rb + row;
        float4 lo = make_float4(0.f,0.f,0.f,0.f);
        float4 hi = make_float4(0.f,0.f,0.f,0.f);
        if (r < M){
          lo = *(const float4*)(A + (size_t)r*512 + kb + k4);
          hi = *(const float4*)(A + (size_t)r*512 + (508 - kb - k4));
        }
        // mirror of col (kb+k4+c) is component (3-c) of hi
        Ae[k4+0][row] = lo.x + hi.w;  Ao[k4+0][row] = lo.x - hi.w;
        Ae[k4+1][row] = lo.y + hi.z;  Ao[k4+1][row] = lo.y - hi.z;
        Ae[k4+2][row] = lo.z + hi.y;  Ao[k4+2][row] = lo.z - hi.y;
        Ae[k4+3][row] = lo.w + hi.x;  Ao[k4+3][row] = lo.w - hi.x;
      }
    } else {
      #pragma unroll
      for (int i=0;i<8;i++){
        int idx = tid + i*256;              // 2048: 128 rows x 16 float4
        int row = idx >> 4, c0 = (idx & 15)*4;   // natural col offset 0..60
        int r = rb + row;
        float4 v = make_float4(0.f,0.f,0.f,0.f);
        if (r < M) v = *(const float4*)(A + (size_t)r*512 + 2*kb + c0);
        int kk = c0 >> 1;
        Ae[kk+0][row] = v.x;  Ao[kk+0][row] = v.y;
        Ae[kk+1][row] = v.z;  Ao[kk+1][row] = v.w;
      }
    }
    #pragma unroll
    for (int i=0;i<2;i++){
      int idx = tid + i*256;                // 512: 64 c x 8 float4
      int crow = idx >> 3, k4 = (idx & 7)*4;
      int c = cb + crow;
      float4 ve = *(const float4*)(BE + (size_t)c*256 + kb + k4);
      float4 vo = *(const float4*)(BO + (size_t)c*256 + kb + k4);
      Be[k4+0][crow]=ve.x; Be[k4+1][crow]=ve.y; Be[k4+2][crow]=ve.z; Be[k4+3][crow]=ve.w;
      Bo[k4+0][crow]=vo.x; Bo[k4+1][crow]=vo.y; Bo[k4+2][crow]=vo.z; Bo[k4+3][crow]=vo.w;
    }
    __syncthreads();
    #pragma unroll
    for (int kk=0; kk<32; kk++){
      const float4 ae0 = *(const float4*)&Ae[kk][ty*8];
      const float4 ae1 = *(const float4*)&Ae[kk][ty*8+4];
      const float4 ao0 = *(const float4*)&Ao[kk][ty*8];
      const float4 ao1 = *(const float4*)&Ao[kk][ty*8+4];
      const float4 be  = *(const float4*)&Be[kk][tx*4];
      const float4 bo  = *(const float4*)&Bo[kk][tx*4];
      float aev[8]={ae0.x,ae0.y,ae0.z,ae0.w,ae1.x,ae1.y,ae1.z,ae1.w};
      float aov[8]={ao0.x,ao0.y,ao0.z,ao0.w,ao1.x,ao1.y,ao1.z,ao1.w};
      float bev[4]={be.x,be.y,be.z,be.w};
      float bov[4]={bo.x,bo.y,bo.z,bo.w};
      #pragma unroll
      for (int i=0;i<8;i++)
        #pragma unroll
        for (int j=0;j<4;j++){
          accE[i][j]=fmaf(aev[i],bev[j],accE[i][j]);
          accO[i][j]=fmaf(aov[i],bov[j],accO[i][j]);
        }
    }
    __syncthreads();
  }

  const int c0 = cb + tx*4;                  // dual index base (0..255)
  #pragma unroll
  for (int i=0;i<8;i++){
    const int r = rb + ty*8 + i;
    if (r >= M) continue;
    if constexpr (OP==0){
      float4 o0 = make_float4(accE[i][0]*p0[2*c0+0], accO[i][0]*p0[2*c0+1],
                              accE[i][1]*p0[2*c0+2], accO[i][1]*p0[2*c0+3]);
      float4 o1 = make_float4(accE[i][2]*p0[2*c0+4], accO[i][2]*p0[2*c0+5],
                              accE[i][3]*p0[2*c0+6], accO[i][3]*p0[2*c0+7]);
      *(float4*)(C + (size_t)r*512 + 2*c0)     = o0;
      *(float4*)(C + (size_t)r*512 + 2*c0 + 4) = o1;
    } else if constexpr (OP==2){
      int d = r % DD;
      float w = p0[d], bo = p1[d];           // Af / Cf
      float4 o0 = make_float4(gelu_f(accE[i][0]*p3[2*c0+0])*w+bo,
                              gelu_f(accO[i][0]*p3[2*c0+1])*w+bo,
                              gelu_f(accE[i][1]*p3[2*c0+2])*w+bo,
                              gelu_f(accO[i][1]*p3[2*c0+3])*w+bo);
      float4 o1 = make_float4(gelu_f(accE[i][2]*p3[2*c0+4])*w+bo,
                              gelu_f(accO[i][2]*p3[2*c0+5])*w+bo,
                              gelu_f(accE[i][3]*p3[2*c0+6])*w+bo,
                              gelu_f(accO[i][3]*p3[2*c0+7])*w+bo);
      *(float4*)(C + (size_t)r*512 + 2*c0)     = o0;
      *(float4*)(C + (size_t)r*512 + 2*c0 + 4) = o1;
    } else {   // OP==1, l = c0..c0+3 and mirrors 511-l
      int d = r % DD;
      float w = p0[d], bo = p1[d];           // conv1_w / conv1_b
      float4 xf = *(const float4*)(p2 + (size_t)r*512 + c0);
      float4 xr = *(const float4*)(p2 + (size_t)r*512 + 508 - c0);
      float4 of, orv;
      of.x = accE[i][0]+accO[i][0] + xf.x*w+bo;
      of.y = accE[i][1]+accO[i][1] + xf.y*w+bo;
      of.z = accE[i][2]+accO[i][2] + xf.z*w+bo;
      of.w = accE[i][3]+accO[i][3] + xf.w*w+bo;
      orv.x = accE[i][3]-accO[i][3] + xr.x*w+bo;
      orv.y = accE[i][2]-accO[i][2] + xr.y*w+bo;
      orv.z = accE[i][1]-accO[i][1] + xr.z*w+bo;
      orv.w = accE[i][0]-accO[i][0] + xr.w*w+bo;
      *(float4*)(C + (size_t)r*512 + c0)       = of;
      *(float4*)(C + (size_t)r*512 + 508 - c0) = orv;
    }
  }
}

// ---------------- generic NT GEMM (96-col paths) ----------------------------
// OP=3: gelu(acc+fc1_b[c]) -> h.   OP=4: acc + cres[c] -> zres.
template<int OP>
__global__ __launch_bounds__(256)
void gemm_nt(const float* __restrict__ A, const float* __restrict__ B,
             float* __restrict__ C, int M, int Ncols, int ldc,
             const float* __restrict__ p0)
{
  __shared__ float As[32][132];
  __shared__ float Bs[32][68];
  const int tid = threadIdx.x;
  const int tx = tid & 15, ty = tid >> 4;
  const int rb = blockIdx.y * 128, cb = blockIdx.x * 64;

  float acc[8][4];
  #pragma unroll
  for (int i=0;i<8;i++)
    #pragma unroll
    for (int j=0;j<4;j++) acc[i][j]=0.f;

  for (int kb=0; kb<512; kb+=32){
    #pragma unroll
    for (int i=0;i<4;i++){
      int idx = tid + i*256;
      int row = idx >> 3, k4 = (idx & 7)*4;
      float4 v = make_float4(0.f,0.f,0.f,0.f);
      int r = rb + row;
      if (r < M) v = *reinterpret_cast<const float4*>(A + (size_t)r*512 + kb + k4);
      As[k4+0][row]=v.x; As[k4+1][row]=v.y; As[k4+2][row]=v.z; As[k4+3][row]=v.w;
    }
    #pragma unroll
    for (int i=0;i<2;i++){
      int idx = tid + i*256;
      int row = idx >> 3, k4 = (idx & 7)*4;
      float4 v = make_float4(0.f,0.f,0.f,0.f);
      int c = cb + row;
      if (c < Ncols) v = *reinterpret_cast<const float4*>(B + (size_t)c*512 + kb + k4);
      Bs[k4+0][row]=v.x; Bs[k4+1][row]=v.y; Bs[k4+2][row]=v.z; Bs[k4+3][row]=v.w;
    }
    __syncthreads();
    #pragma unroll
    for (int kk=0; kk<32; kk++){
      const float4 a0 = *reinterpret_cast<const float4*>(&As[kk][ty*8]);
      const float4 a1 = *reinterpret_cast<const float4*>(&As[kk][ty*8+4]);
      const float4 b0 = *reinterpret_cast<const float4*>(&Bs[kk][tx*4]);
      float av[8]={a0.x,a0.y,a0.z,a0.w,a1.x,a1.y,a1.z,a1.w};
      float bv[4]={b0.x,b0.y,b0.z,b0.w};
      #pragma unroll
      for (int i=0;i<8;i++)
        #pragma unroll
        for (int j=0;j<4;j++) acc[i][j]=fmaf(av[i],bv[j],acc[i][j]);
    }
    __syncthreads();
  }

  #pragma unroll
  for (int i=0;i<8;i++){
    const int r = rb + ty*8 + i;
    if (r >= M) continue;
    #pragma unroll
    for (int j=0;j<4;j++){
      int c = cb + tx*4 + j;
      if (c < Ncols){
        if constexpr (OP==3) C[(size_t)r*ldc + c] = gelu_f(acc[i][j] + p0[c]);
        else                 C[(size_t)r*ldc + c] = acc[i][j] + p0[c];
      }
    }
  }
}

// ---------------- energy per row (deterministic) ----------------------------
__global__ __launch_bounds__(256)
void k_energy(const float* __restrict__ zdct, float* __restrict__ energy)
{
  int r=blockIdx.x, tid=threadIdx.x;
  __shared__ float rbuf[256];
  float acc=0.f;
  for (int k=tid;k<512;k+=256){ float v=zdct[(size_t)r*512+k]; acc=fmaf(v,v,acc); }
  rbuf[tid]=acc; __syncthreads();
  for (int st=128;st>0;st>>=1){ if(tid<st) rbuf[tid]+=rbuf[tid+st]; __syncthreads(); }
  if (tid==0) energy[r]=rbuf[0];
}

// ---------------- median over D per batch, ne = e/(med+1e-6) ----------------
__global__ __launch_bounds__(256)
void k3_median(const float* __restrict__ energy, float* __restrict__ ne)
{
  int b = blockIdx.x, tid=threadIdx.x;
  __shared__ float e[DD];
  __shared__ float medv;
  for (int i=tid;i<DD;i+=256) e[i]=energy[b*DD+i];
  __syncthreads();
  for (int i=tid;i<DD;i+=256){
    float v=e[i]; int lt=0, eq=0;
    for (int j=0;j<DD;j++){ float u=e[j]; lt += (u<v); eq += (u==v); }
    if (lt<=160 && 160<lt+eq) medv=v;      // 0-based rank 160 of 321
  }
  __syncthreads();
  float den = medv + 1e-6f;
  for (int i=tid;i<DD;i+=256) ne[b*DD+i] = e[i]/den;
}

// ---------------- quantile via radix select (2 ranks + lerp) ----------------
__global__ __launch_bounds__(1024)
void k3_thr(const float* __restrict__ ne, const float* __restrict__ thrin,
            float* __restrict__ out)
{
  __shared__ int hist[256];
  __shared__ unsigned sPrefix; __shared__ int sRank;
  int tid = threadIdx.x;
  float q = fminf(fmaxf(thrin[0],0.f),1.f);
  float pos = q * (float)(M_ROWS-1);
  int lo = (int)floorf(pos); int hi = (int)ceilf(pos);
  float frac = pos - floorf(pos);
  float vals[2];
  for (int s=0;s<2;s++){
    int rank = s ? hi : lo;
    unsigned prefix=0, pmask=0;
    for (int pass=0; pass<4; pass++){
      int shift = 24 - 8*pass;
      if (tid<256) hist[tid]=0;
      __syncthreads();
      for (int i=tid;i<M_ROWS;i+=1024){
        unsigned u = __float_as_uint(ne[i]);
        if ((u & pmask)==prefix) atomicAdd(&hist[(u>>shift)&255u],1);
      }
      __syncthreads();
      if (tid==0){
        int cum=0;
        for (int bkt=0;bkt<256;bkt++){
          int c=hist[bkt];
          if (cum + c > rank){ sPrefix = prefix | ((unsigned)bkt<<(unsigned)shift); sRank = rank - cum; break; }
          cum += c;
        }
      }
      __syncthreads();
      prefix = sPrefix; rank = sRank; pmask |= (0xFFu<<(unsigned)shift);
      __syncthreads();
    }
    vals[s] = __uint_as_float(prefix);
  }
  if (tid==0) out[0] = vals[0]*(1.0f-frac) + vals[1]*frac;
}

// ---------------- in-place transform of zdct before IDCT --------------------
__global__ void k4_pre(float* __restrict__ zdct, const float* __restrict__ ne,
                       const float* __restrict__ thr, const float* __restrict__ w1,
                       const float* __restrict__ b1, const float* __restrict__ dvec)
{
  size_t idx = (size_t)blockIdx.x*256 + threadIdx.x;   // over 10272*128 float4
  int r = (int)(idx>>7);
  int k0 = ((int)idx & 127)*4;
  float m  = (ne[r] > thr[0]) ? 1.f : 0.f;
  int d = r % DD;
  float w = w1[d]*m, bo = b1[d];
  float4 v = ((float4*)zdct)[idx];
  v.x = gelu_f(fmaf(v.x,w,bo))/dvec[k0+0];
  v.y = gelu_f(fmaf(v.y,w,bo))/dvec[k0+1];
  v.z = gelu_f(fmaf(v.z,w,bo))/dvec[k0+2];
  v.w = gelu_f(fmaf(v.w,w,bo))/dvec[k0+3];
  ((float4*)zdct)[idx]=v;
}

// ---------------- z2: per-patch 16x16 matmul + gelu -------------------------
__global__ __launch_bounds__(256)
void k5_z2(const float* __restrict__ xt, const float* __restrict__ Mp,
           const float* __restrict__ c2p, float* __restrict__ z2)
{
  int r = blockIdx.x, tid=threadIdx.x;
  __shared__ float row[512];
  for (int i=tid;i<512;i+=256) row[i]=xt[(size_t)r*512+i];
  __syncthreads();
  for (int idx=tid; idx<512; idx+=256){
    int n = idx>>4, p = idx&15;
    float acc = c2p[idx];
    const float* Mn = Mp + n*256 + p;
    #pragma unroll
    for (int qq=0;qq<16;qq++) acc = fmaf(row[n*16+qq], Mn[qq*16], acc);
    z2[(size_t)r*512+idx] = gelu_f(acc);
  }
}

// ---------------- fused convs / gates / z1c / att-dot -----------------------
__global__ __launch_bounds__(256)
void k7_fuse(const float* __restrict__ z1, const float* __restrict__ z2f,
             const float* __restrict__ z2, float* __restrict__ z1c,
             float* __restrict__ zdpre,
             const float* __restrict__ c2w, const float* __restrict__ c2b,
             const float* __restrict__ c3w, const float* __restrict__ c3b,
             const float* __restrict__ Af,  const float* __restrict__ Cf,
             const float* __restrict__ dns, const float* __restrict__ Bf,
             const float* __restrict__ catt)
{
  int r = blockIdx.x, tid=threadIdx.x;
  int d = r % DD;
  __shared__ float zrow[518];
  __shared__ float rbuf[256];
  for (int i=tid;i<518;i+=256){
    int l = i-3;
    zrow[i] = (l>=0 && l<512) ? z1[(size_t)r*512+l] : 0.f;
  }
  __syncthreads();
  float w2[5], w3[7];
  #pragma unroll
  for (int t=0;t<5;t++) w2[t]=c2w[d*5+t];
  #pragma unroll
  for (int t=0;t<7;t++) w3[t]=c3w[d*7+t];
  const float cb2=c2b[d], cb3=c3b[d];
  const float af=Af[d], cf=Cf[d], s=dns[d], bf=Bf[d];
  float dotacc=0.f;
  for (int l=tid;l<512;l+=256){
    float c5=cb2;
    #pragma unroll
    for (int t=0;t<5;t++) c5 = fmaf(zrow[l+t+1], w2[t], c5);   // pad-2 conv k=5
    float zr  = sigmoid_f(fmaf(gelu_f(c5),af,cf));
    float zgv = gelu_f(z2f[(size_t)r*512+l]*zr);
    float c7=cb3;
    #pragma unroll
    for (int t=0;t<7;t++) c7 = fmaf(zrow[l+t], w3[t], c7);     // pad-3 conv k=7
    float z1b = gelu_f(fmaf(c7,s,bf));
    float v = fmaf(zgv,s,bf) + z1b;                            // z1c = bnD(zg)+z1b
    z1c[(size_t)r*512+l]=v;
    dotacc = fmaf(v*z2[(size_t)r*512+l], catt[l], dotacc);
  }
  rbuf[tid]=dotacc; __syncthreads();
  for (int st=128;st>0;st>>=1){ if(tid<st) rbuf[tid]+=rbuf[tid+st]; __syncthreads(); }
  if (tid==0) zdpre[r]=rbuf[0];
}

// ---------------- attention scalar path + softmax over D --------------------
__global__ __launch_bounds__(256)
void k8_att(const float* __restrict__ zdpre, float* __restrict__ att1,
            const float* __restrict__ adwb, const float* __restrict__ acw,
            const float* __restrict__ acb,  const float* __restrict__ ag,
            const float* __restrict__ ab,   const float* __restrict__ am,
            const float* __restrict__ av)
{
  int b=blockIdx.x, t=threadIdx.x;
  __shared__ float sred[256];
  float vloc[2];
  float mx=-INFINITY;
  float sA = ag[0]/sqrtf(av[0]+1e-5f);
  #pragma unroll
  for (int ii=0;ii<2;ii++){
    int d=t+ii*256;
    float v=-INFINITY;
    if (d<DD){
      float zd = zdpre[b*DD+d] + adwb[0];
      zd = gelu_f(zd);
      zd = (zd-am[0])*sA + ab[0];
      zd = zd*acw[0] + acb[0];
      v=zd;
    }
    vloc[ii]=v; mx=fmaxf(mx,v);
  }
  sred[t]=mx; __syncthreads();
  for (int st=128;st>0;st>>=1){ if (t<st) sred[t]=fmaxf(sred[t],sred[t+st]); __syncthreads(); }
  float m=sred[0]; __syncthreads();
  float e0 = (t<DD)     ? expf(vloc[0]-m) : 0.f;
  float e1 = (t+256<DD) ? expf(vloc[1]-m) : 0.f;
  sred[t]=e0+e1; __syncthreads();
  for (int st=128;st>0;st>>=1){ if (t<st) sred[t]+=sred[t+st]; __syncthreads(); }
  float sum=sred[0];
  if (t<DD)     att1[b*DD+t]     = e0/sum;
  if (t+256<DD) att1[b*DD+t+256] = e1/sum;
}

// ---------------- zf = z1c*att + z2*(1-att) ---------------------------------
__global__ void k8b_zf(const float* __restrict__ z1c, const float* __restrict__ z2,
                       const float* __restrict__ att1, float* __restrict__ zf)
{
  size_t idx = (size_t)blockIdx.x*256 + threadIdx.x;   // over 10272*128 float4
  int r = (int)(idx>>7);
  float a = att1[r];
  float4 v1 = ((const float4*)z1c)[idx];
  float4 v2 = ((const float4*)z2)[idx];
  float4 o;
  o.x = v1.x*a + v2.x*(1.f-a);
  o.y = v1.y*a + v2.y*(1.f-a);
  o.z = v1.z*a + v2.z*(1.f-a);
  o.w = v1.w*a + v2.w*(1.f-a);
  ((float4*)zf)[idx]=o;
}

// ---------------- final: out = h@fc2 + fc2_b + zres, transposed store -------
__global__ __launch_bounds__(256)
void k9_final(const float* __restrict__ h, const float* __restrict__ zres,
              const float* __restrict__ fc2_w, const float* __restrict__ fc2_b,
              float* __restrict__ outF)
{
  int b = blockIdx.y; int d0 = blockIdx.x*32;
  __shared__ float f2[96*96];
  __shared__ float hs[32][97];
  __shared__ float zs[32][97];
  int tid=threadIdx.x;
  for (int i=tid;i<96*96;i+=256) f2[i]=fc2_w[i];
  for (int i=tid;i<32*96;i+=256){
    int dl = i/96, p = i%96; int d = d0+dl;
    float hv=0.f, zv=0.f;
    if (d<DD){ hv = h[((size_t)b*DD+d)*96+p]; zv = zres[((size_t)b*DD+d)*96+p]; }
    hs[dl][p]=hv; zs[dl][p]=zv;
  }
  __syncthreads();
  int tx = tid & 31, ty = tid >> 5;
  int d = d0+tx;
  float acc[12];
  #pragma unroll
  for (int kc=0;kc<12;kc++) acc[kc]=0.f;
  for (int p=0;p<96;p++){
    float hv = hs[tx][p];
    #pragma unroll
    for (int kc=0;kc<12;kc++) acc[kc] = fmaf(hv, f2[p*96 + ty + kc*8], acc[kc]);
  }
  if (d<DD){
    #pragma unroll
    for (int kc=0;kc<12;kc++){
      int c = ty + kc*8;
      outF[((size_t)b*96 + c)*DD + d] = acc[kc] + fc2_b[c] + zs[tx][c];
    }
  }
}

// ---------------------------------------------------------------------------
extern "C" void kernel_launch(void* const* d_in, const int* in_sizes, int n_in,
                              void* d_out, int out_size, void* d_ws, size_t ws_size,
                              hipStream_t stream)
{
  (void)in_sizes; (void)n_in; (void)out_size; (void)ws_size;
  const float* x        =(const float*)d_in[0];
  const float* conv1_w  =(const float*)d_in[1];
  const float* conv1_b  =(const float*)d_in[2];
  const float* conv2_w  =(const float*)d_in[3];
  const float* conv2_b  =(const float*)d_in[4];
  const float* conv3_w  =(const float*)d_in[5];
  const float* conv3_b  =(const float*)d_in[6];
  const float* dn_g     =(const float*)d_in[7];
  const float* dn_b     =(const float*)d_in[8];
  const float* dn_m     =(const float*)d_in[9];
  const float* dn_v     =(const float*)d_in[10];
  const float* pn_g     =(const float*)d_in[11];
  const float* pn_b     =(const float*)d_in[12];
  const float* pn_m     =(const float*)d_in[13];
  const float* pn_v     =(const float*)d_in[14];
  const float* embed_w  =(const float*)d_in[15];
  const float* embed_b  =(const float*)d_in[16];
  const float* lin_res_w=(const float*)d_in[17];
  const float* lin_res_b=(const float*)d_in[18];
  const float* depth_res_w=(const float*)d_in[19];
  const float* depth_res_b=(const float*)d_in[20];
  const float* depth_conv_w=(const float*)d_in[21];
  const float* depth_conv_b=(const float*)d_in[22];
  const float* threshold=(const float*)d_in[23];
  const float* att_dw_w =(const float*)d_in[24];
  const float* att_dw_b =(const float*)d_in[25];
  const float* att_conv_w=(const float*)d_in[26];
  const float* att_conv_b=(const float*)d_in[27];
  const float* att_g    =(const float*)d_in[28];
  const float* att_b    =(const float*)d_in[29];
  const float* att_m    =(const float*)d_in[30];
  const float* att_v    =(const float*)d_in[31];
  const float* fc1_w    =(const float*)d_in[32];
  const float* fc1_b    =(const float*)d_in[33];
  const float* fc2_w    =(const float*)d_in[34];
  const float* fc2_b    =(const float*)d_in[35];

  float* ws   = (float*)d_ws;
  float* CoE  = ws + OFF_COE;
  float* CoO  = ws + OFF_COO;
  float* CoET = ws + OFF_COET;
  float* CoOT = ws + OFF_COOT;
  float* dvec = ws + OFF_DVEC;
  float* catt = ws + OFF_CATT;
  float* fc1T = ws + OFF_FC1T;
  float* WeffT= ws + OFF_WEFFT;
  float* cres = ws + OFF_CRES;
  float* Mp   = ws + OFF_MP;
  float* c2p  = ws + OFF_C2P;
  float* Af   = ws + OFF_AF;
  float* Cf   = ws + OFF_CF;
  float* dns  = ws + OFF_DNS;
  float* Bf   = ws + OFF_BF;
  float* energy=ws + OFF_EN;
  float* ne   = ws + OFF_NE;
  float* thr  = ws + OFF_THR;
  float* zdpre= ws + OFF_ZDP;
  float* att1 = ws + OFF_ATT1;
  float* xt   = ws + OFF_XT;
  float* zdct = ws + OFF_ZDCT;   // later reused as z2f
  float* z1   = ws + OFF_Z1;     // later reused as zf
  float* z2   = ws + OFF_Z2;
  float* z1c  = ws + OFF_Z1C;
  float* h    = ws + OFF_H;
  float* zres = ws + OFF_ZRES;
  float* Wpart= ws + OFF_WPART;
  float* pcres= ws + OFF_PCRES;

  // --- precompute ---
  k0_dctF <<<256, 256, 0, stream>>>(CoE, CoO, CoET, CoOT, dvec, catt, att_dw_w);
  kA_weff <<<dim3(32,4), 256, 0, stream>>>(embed_w, embed_b, lin_res_w, Wpart, pcres);
  kA_fin  <<<193, 256, 0, stream>>>(Wpart, pcres, lin_res_b, WeffT, cres);
  kT_fc1  <<<dim3(3,16), 256, 0, stream>>>(fc1_w, fc1T);
  k0_depth<<<32, 256, 0, stream>>>(embed_w, embed_b, depth_res_w, depth_res_b,
                                   depth_conv_w, depth_conv_b, pn_g, pn_b, pn_m, pn_v,
                                   Mp, c2p);
  k0_fold <<<2, 256, 0, stream>>>(conv1_w, conv1_b, dn_g, dn_b, dn_m, dn_v,
                                  Af, Cf, dns, Bf);

  // --- transpose, DCT(x), mask stats ---
  k1_transpose<<<dim3(11,16,BB), 256, 0, stream>>>(x, xt);
  gemm_dual<0><<<dim3(4,81), 256, 0, stream>>>(xt, CoE, CoO, zdct, M_ROWS,
                                               dvec, nullptr, nullptr, nullptr);
  k_energy <<<M_ROWS, 256, 0, stream>>>(zdct, energy);
  k3_median<<<BB, 256, 0, stream>>>(energy, ne);
  k3_thr   <<<1, 1024, 0, stream>>>(ne, threshold, thr);

  // --- z1 = idct(gelu(conv1(mask*zdct))) + freq_res ---
  k4_pre   <<<5136, 256, 0, stream>>>(zdct, ne, thr, conv1_w, conv1_b, dvec);
  gemm_dual<1><<<dim3(4,81), 256, 0, stream>>>(zdct, CoET, CoOT, z1, M_ROWS,
                                               conv1_w, conv1_b, xt, nullptr);

  // --- z2 (patch path), z2_f = conv1(bnD(gelu(dct(z2)))) into zdct buf ---
  k5_z2    <<<M_ROWS, 256, 0, stream>>>(xt, Mp, c2p, z2);
  gemm_dual<2><<<dim3(4,81), 256, 0, stream>>>(z2, CoE, CoO, zdct, M_ROWS,
                                               Af, Cf, nullptr, dvec);

  // --- convs, gates, z1c, att-dot ---
  k7_fuse  <<<M_ROWS, 256, 0, stream>>>(z1, zdct, z2, z1c, zdpre,
                                        conv2_w, conv2_b, conv3_w, conv3_b,
                                        Af, Cf, dns, Bf, catt);
  k8_att   <<<BB, 256, 0, stream>>>(zdpre, att1, att_dw_b, att_conv_w, att_conv_b,
                                    att_g, att_b, att_m, att_v);
  k8b_zf   <<<5136, 256, 0, stream>>>(z1c, z2, att1, z1);   // zf into z1 buf

  // --- MLP head + linear residual, transposed store ---
  gemm_nt<3><<<dim3(2,81), 256, 0, stream>>>(z1, fc1T, h, M_ROWS, 96, 96, fc1_b);
  gemm_nt<4><<<dim3(2,81), 256, 0, stream>>>(xt, WeffT, zres, M_ROWS, 96, 96, cres);
  k9_final <<<dim3(11,BB), 256, 0, stream>>>(h, zres, fc2_w, fc2_b, (float*)d_out);
}

// Round 9
// 723.364 us; speedup vs baseline: 1.2416x; 1.0603x over previous
//
#include <hip/hip_runtime.h>
#include <cmath>

// ---------------------------------------------------------------------------
// Backbone forward (B=32, L=512, D=321, P=16, N=32, dm=256, pred=96), fp32.
// Round 9 (= round 5 resubmit #4): occupancy-tiled dual GEMM (64x32x128thr,
// 1288 blocks), merged 96-col GEMMs with fused zf blend.
// ---------------------------------------------------------------------------

#define BB   32
#define LL   512
#define DD   321
#define PRED 96
#define M_ROWS (BB*DD)          // 10272 rows of length 512

__device__ __forceinline__ float gelu_f(float x){
  return 0.5f*x*(1.0f + erff(x*0.70710678118654752440f));
}
__device__ __forceinline__ float sigmoid_f(float x){
  return 1.0f/(1.0f+expf(-x));
}

// ---------------- workspace layout (floats) --------------------------------
constexpr size_t OFF_COE  = 0;                        // CoE [256][256]
constexpr size_t OFF_COO  = OFF_COE  + 256*256;       // CoO [256][256]
constexpr size_t OFF_COET = OFF_COO  + 256*256;       // CoET[256][256]
constexpr size_t OFF_COOT = OFF_COET + 256*256;       // CoOT[256][256]
constexpr size_t OFF_DVEC = OFF_COOT + 256*256;       // dvec[512]
constexpr size_t OFF_CATT = OFF_DVEC + 512;           // catt[512]
constexpr size_t OFF_FC1T = OFF_CATT + 512;           // fc1T[96][512]
constexpr size_t OFF_WEFFT= OFF_FC1T + 96*512;        // WeffT[96][512]
constexpr size_t OFF_CRES = OFF_WEFFT+ 96*512;        // cres[96] (pad 128)
constexpr size_t OFF_MP   = OFF_CRES + 128;           // M'[32][16][16]
constexpr size_t OFF_C2P  = OFF_MP   + 32*256;        // c2'[32][16]
constexpr size_t OFF_AF   = OFF_C2P  + 512;           // Af[321] pad 384
constexpr size_t OFF_CF   = OFF_AF   + 384;
constexpr size_t OFF_DNS  = OFF_CF   + 384;
constexpr size_t OFF_BF   = OFF_DNS  + 384;
constexpr size_t OFF_EN   = OFF_BF   + 384;           // energy[10272] pad 10368
constexpr size_t OFF_NE   = OFF_EN   + 10368;         // ne[10272]
constexpr size_t OFF_THR  = OFF_NE   + 10368;         // thr scalar (pad 64)
constexpr size_t OFF_ZDP  = OFF_THR  + 64;            // zdpre[10272]
constexpr size_t OFF_ATT1 = OFF_ZDP  + 10368;         // att1[10272]
constexpr size_t OFF_XT   = OFF_ATT1 + 10368;         // xt  [10272][512]
constexpr size_t OFF_ZDCT = OFF_XT   + (size_t)M_ROWS*512; // zdct (reused z2f)
constexpr size_t OFF_Z1   = OFF_ZDCT + (size_t)M_ROWS*512;
constexpr size_t OFF_Z2   = OFF_Z1   + (size_t)M_ROWS*512;
constexpr size_t OFF_Z1C  = OFF_Z2   + (size_t)M_ROWS*512;
constexpr size_t OFF_H    = OFF_Z1C  + (size_t)M_ROWS*512; // h[10272][96]
constexpr size_t OFF_ZRES = OFF_H    + (size_t)M_ROWS*96;  // zres[10272][96]
constexpr size_t OFF_WPART= OFF_ZRES + (size_t)M_ROWS*96;  // Wpart[4][96][512]
constexpr size_t OFF_PCRES= OFF_WPART+ 4*96*512;           // pcres[128][96]
constexpr size_t WS_FLOATS= OFF_PCRES+ 128*96;

// ---------------- precompute: even/odd DCT matrices -------------------------
__global__ __launch_bounds__(256)
void k0_dctF(float* __restrict__ CoE, float* __restrict__ CoO,
             float* __restrict__ CoET, float* __restrict__ CoOT,
             float* __restrict__ dvec, float* __restrict__ catt,
             const float* __restrict__ attw)
{
  const float PI_F = 3.14159265358979323846f;
  const float ck0 = 1.0f/sqrtf(512.0f), ckn = sqrtf(2.0f/512.0f);
  int c = blockIdx.x;                 // 0..255
  int t = threadIdx.x;                // 0..255
  {
    float a1 = PI_F * (float)(2*t+1);
    float ckE = (c==0) ? ck0 : ckn;
    float aE = a1 * (float)(2*c);
    float aO = a1 * (float)(2*c+1);
    CoE[c*256+t] = cosf(aE * (1.0f/1024.0f)) * ckE;
    CoO[c*256+t] = cosf(aO * (1.0f/1024.0f)) * ckn;
  }
  {
    float a1 = PI_F * (float)(2*c+1);
    float ckE = (t==0) ? ck0 : ckn;
    float aE = a1 * (float)(2*t);
    float aO = a1 * (float)(2*t+1);
    CoET[c*256+t] = cosf(aE * (1.0f/1024.0f)) * ckE;
    CoOT[c*256+t] = cosf(aO * (1.0f/1024.0f)) * ckn;
  }
  if (t==0){
    dvec[2*c]   = (c==0) ? 2.0f*sqrtf(512.0f) : sqrtf(2.0f*512.0f);
    dvec[2*c+1] = sqrtf(2.0f*512.0f);
  }
  if (c==0){
    for (int l=t; l<512; l+=256){
      float sacc=0.f;
      for (int j=0;j<5;j++){
        float ckj = (j==0)? ck0 : ckn;
        float a1 = PI_F*(float)(2*l+1);
        float a2 = a1*(float)j;
        sacc += cosf(a2 * (1.0f/1024.0f))*ckj*attw[j];
      }
      catt[l]=sacc;
    }
  }
}

// ---------------- precompute: WeffT partials + cres partials ----------------
__global__ __launch_bounds__(256)
void kA_weff(const float* __restrict__ ew_g, const float* __restrict__ eb_g,
             const float* __restrict__ lrw,
             float* __restrict__ Wpart, float* __restrict__ pcres)
{
  const int n = blockIdx.x, kb4 = blockIdx.y;     // K-chunk of 64
  __shared__ float ews[16][68];
  __shared__ float ebs[64];
  __shared__ float lw[64][96];
  const int tid = threadIdx.x;
  const int jbase = kb4*64;
  for (int i=tid; i<1024; i+=256){
    int p2 = i>>6, j2 = i&63;
    ews[p2][j2] = ew_g[p2*256 + jbase + j2];
  }
  if (tid < 64) ebs[tid] = eb_g[jbase + tid];
  for (int i=tid; i<1536; i+=256){                 // lrw slice [64][96] as float4
    int jj = i/24, c4 = i%24;
    *(float4*)&lw[jj][c4*4] =
      *(const float4*)&lrw[((size_t)(n*256 + jbase + jj))*96 + c4*4];
  }
  __syncthreads();
  const int p = tid>>4, tx = tid&15;
  float acc[6]={0,0,0,0,0,0};
  float accB[6]={0,0,0,0,0,0};
  for (int jj=0; jj<64; jj++){
    float a = ews[p][jj];
    #pragma unroll
    for (int g=0; g<6; g++) acc[g] = fmaf(a, lw[jj][tx+16*g], acc[g]);
    if (p==0){
      float bv = ebs[jj];
      #pragma unroll
      for (int g=0; g<6; g++) accB[g] = fmaf(bv, lw[jj][tx+16*g], accB[g]);
    }
  }
  #pragma unroll
  for (int g=0; g<6; g++){
    int pr = tx + 16*g;
    Wpart[((size_t)kb4*96 + pr)*512 + n*16 + p] = acc[g];
    if (p==0) pcres[(n*4+kb4)*96 + pr] = accB[g];
  }
}

// ---------------- reduce WeffT partials + cres ------------------------------
__global__ __launch_bounds__(256)
void kA_fin(const float* __restrict__ Wpart, const float* __restrict__ pcres,
            const float* __restrict__ lrb,
            float* __restrict__ WeffT, float* __restrict__ cres)
{
  int b = blockIdx.x;
  if (b < 192){
    int i = b*256 + threadIdx.x;                   // over 96*512 = 49152
    WeffT[i] = (Wpart[i] + Wpart[49152+i]) + (Wpart[2*49152+i] + Wpart[3*49152+i]);
  } else {
    int pr = threadIdx.x;
    if (pr < 96){
      float s = lrb[pr];
      for (int nn=0; nn<128; nn++) s += pcres[nn*96+pr];
      cres[pr] = s;
    }
  }
}

// ---------------- fc1T = transpose(fc1_w [512][96]) -------------------------
__global__ __launch_bounds__(256)
void kT_fc1(const float* __restrict__ fc1_w, float* __restrict__ fc1T)
{
  __shared__ float t[32][33];
  int c0 = blockIdx.x*32;   // over 96
  int l0 = blockIdx.y*32;   // over 512
  int tid=threadIdx.x; int j=tid&31, i0=tid>>5;
  for (int ii=0; ii<32; ii+=8){
    int l=l0+i0+ii, c=c0+j;
    t[i0+ii][j] = (c<96)? fc1_w[l*96+c] : 0.f;
  }
  __syncthreads();
  for (int ii=0; ii<32; ii+=8){
    int c=c0+i0+ii, l=l0+j;
    if (c<96) fc1T[(size_t)c*512 + l] = t[j][i0+ii];
  }
}

// ---------------- precompute: patch matrix M' (+BN fold) --------------------
__global__ __launch_bounds__(256)
void k0_depth(const float* __restrict__ embed_w, const float* __restrict__ embed_b,
              const float* __restrict__ drw, const float* __restrict__ drb,
              const float* __restrict__ dcw, const float* __restrict__ dcb,
              const float* __restrict__ png, const float* __restrict__ pnb,
              const float* __restrict__ pnm, const float* __restrict__ pnv,
              float* __restrict__ Mp, float* __restrict__ c2p)
{
  int n = blockIdx.x; int tid = threadIdx.x;
  int q = tid>>4, p = tid&15;
  float acc = 0.f;                       // depth_conv part
  for (int j=0;j<16;j++)  acc = fmaf(embed_w[q*256 + p*16 + j], dcw[n*16+j], acc);
  float wtr = 0.f;                       // time_res part
  for (int j=0;j<256;j++) wtr = fmaf(embed_w[q*256 + j], drw[j*16+p], wtr);
  float sn = png[n]/sqrtf(pnv[n]+1e-5f);
  Mp[n*256 + q*16 + p] = (acc + wtr) * sn;
  if (q==0){
    float c = dcb[n];
    for (int j=0;j<16;j++)  c = fmaf(embed_b[p*16+j], dcw[n*16+j], c);
    float ctr = drb[p];
    for (int j=0;j<256;j++) ctr = fmaf(embed_b[j], drw[j*16+p], ctr);
    c += ctr;
    c2p[n*16+p] = (c - pnm[n])*sn + pnb[n];
  }
}

// ---------------- precompute: per-channel BN/conv1 folds --------------------
__global__ void k0_fold(const float* __restrict__ w1, const float* __restrict__ b1,
                        const float* __restrict__ g,  const float* __restrict__ bbq,
                        const float* __restrict__ mq, const float* __restrict__ vq,
                        float* __restrict__ Af, float* __restrict__ Cf,
                        float* __restrict__ dns, float* __restrict__ Bf)
{
  int d = blockIdx.x*256 + threadIdx.x;
  if (d >= DD) return;
  float s  = g[d]/sqrtf(vq[d]+1e-5f);
  float bf = bbq[d] - mq[d]*s;
  dns[d]=s; Bf[d]=bf; Af[d]=s*w1[d]; Cf[d]=bf*w1[d]+b1[d];
}

// ---------------- transpose x[B,L,D] -> xt[B*D,512] -------------------------
__global__ __launch_bounds__(256)
void k1_transpose(const float* __restrict__ x, float* __restrict__ xt)
{
  int b = blockIdx.z; int l0 = blockIdx.y*32; int d0 = blockIdx.x*32;
  __shared__ float t[32][33];
  int tid=threadIdx.x; int j = tid&31, i0 = tid>>5;
  for (int ii=0; ii<32; ii+=8){
    int l = l0 + i0+ii; int d = d0 + j;
    t[i0+ii][j] = (d<DD) ? x[((size_t)b*512 + l)*DD + d] : 0.f;
  }
  __syncthreads();
  for (int ii=0; ii<32; ii+=8){
    int d = d0 + i0+ii; int l = l0 + j;
    if (d<DD) xt[((size_t)b*DD+d)*512 + l] = t[j][i0+ii];
  }
}

// ---------------- dual even/odd GEMM for DCT/IDCT (K'=256) ------------------
// 64 rows x 32 dual-cols per block, 128 threads, 4x4 dual micro-tile.
// OP=0 (DCT): fold staging u/v; C[r][2c]=accE*dv, C[r][2c+1]=accO*dv.
// OP=2 (DCT of z2): same; C = gelu(acc*dv)*Af[d] + Cf[d].
// OP=1 (IDCT): deinterleave staging; C[r][l]=E+O+fr(l); C[r][511-l]=E-O+fr().
template<int OP>
__global__ __launch_bounds__(128, 4)
void gemm_dual(const float* __restrict__ A, const float* __restrict__ BE,
               const float* __restrict__ BO, float* __restrict__ C, int M,
               const float* __restrict__ p0, const float* __restrict__ p1,
               const float* __restrict__ p2)
{
  __shared__ float Ae[32][68];
  __shared__ float Ao[32][68];
  __shared__ float Be[32][36];
  __shared__ float Bo[32][36];
  const int tid = threadIdx.x;
  const int tx = tid & 7, ty = tid >> 3;          // tx: 8 col-grp, ty: 16 row-grp
  const int rb = blockIdx.y * 64, cb = blockIdx.x * 32;   // cb: dual-col base
  const float dv0 = 45.25483399593904f, dvn = 32.0f;

  float accE[4][4], accO[4][4];
  #pragma unroll
  for (int i=0;i<4;i++)
    #pragma unroll
    for (int j=0;j<4;j++){ accE[i][j]=0.f; accO[i][j]=0.f; }

  for (int kb=0; kb<256; kb+=32){
    if constexpr (OP==0 || OP==2){
      #pragma unroll
      for (int i=0;i<4;i++){
        int idx = tid + i*128;              // 512: 64 rows x 8 float4
        int row = idx >> 3, k4 = (idx & 7)*4;
        int r = rb + row;
        float4 lo = make_float4(0.f,0.f,0.f,0.f);
        float4 hi = make_float4(0.f,0.f,0.f,0.f);
        if (r < M){
          lo = *(const float4*)(A + (size_t)r*512 + kb + k4);
          hi = *(const float4*)(A + (size_t)r*512 + (508 - kb - k4));
        }
        Ae[k4+0][row] = lo.x + hi.w;  Ao[k4+0][row] = lo.x - hi.w;
        Ae[k4+1][row] = lo.y + hi.z;  Ao[k4+1][row] = lo.y - hi.z;
        Ae[k4+2][row] = lo.z + hi.y;  Ao[k4+2][row] = lo.z - hi.y;
        Ae[k4+3][row] = lo.w + hi.x;  Ao[k4+3][row] = lo.w - hi.x;
      }
    } else {
      #pragma unroll
      for (int i=0;i<8;i++){
        int idx = tid + i*128;              // 1024: 64 rows x 16 float4
        int row = idx >> 4, c0 = (idx & 15)*4;
        int r = rb + row;
        float4 v = make_float4(0.f,0.f,0.f,0.f);
        if (r < M) v = *(const float4*)(A + (size_t)r*512 + 2*kb + c0);
        int kk = c0 >> 1;
        Ae[kk+0][row] = v.x;  Ao[kk+0][row] = v.y;
        Ae[kk+1][row] = v.z;  Ao[kk+1][row] = v.w;
      }
    }
    #pragma unroll
    for (int i=0;i<2;i++){
      int idx = tid + i*128;                // 256: 32 cols x 8 float4
      int crow = idx >> 3, k4 = (idx & 7)*4;
      int c = cb + crow;
      float4 ve = *(const float4*)(BE + (size_t)c*256 + kb + k4);
      float4 vo = *(const float4*)(BO + (size_t)c*256 + kb + k4);
      Be[k4+0][crow]=ve.x; Be[k4+1][crow]=ve.y; Be[k4+2][crow]=ve.z; Be[k4+3][crow]=ve.w;
      Bo[k4+0][crow]=vo.x; Bo[k4+1][crow]=vo.y; Bo[k4+2][crow]=vo.z; Bo[k4+3][crow]=vo.w;
    }
    __syncthreads();
    #pragma unroll
    for (int kk=0; kk<32; kk++){
      const float4 ae = *(const float4*)&Ae[kk][ty*4];
      const float4 ao = *(const float4*)&Ao[kk][ty*4];
      const float4 be = *(const float4*)&Be[kk][tx*4];
      const float4 bo = *(const float4*)&Bo[kk][tx*4];
      float aev[4]={ae.x,ae.y,ae.z,ae.w};
      float aov[4]={ao.x,ao.y,ao.z,ao.w};
      float bev[4]={be.x,be.y,be.z,be.w};
      float bov[4]={bo.x,bo.y,bo.z,bo.w};
      #pragma unroll
      for (int i=0;i<4;i++)
        #pragma unroll
        for (int j=0;j<4;j++){
          accE[i][j]=fmaf(aev[i],bev[j],accE[i][j]);
          accO[i][j]=fmaf(aov[i],bov[j],accO[i][j]);
        }
    }
    __syncthreads();
  }

  const int c0 = cb + tx*4;                  // dual index base (0..255)
  #pragma unroll
  for (int i=0;i<4;i++){
    const int r = rb + ty*4 + i;
    if (r >= M) continue;
    if constexpr (OP==0){
      float d0e = (c0==0) ? dv0 : dvn;
      float4 o0 = make_float4(accE[i][0]*d0e, accO[i][0]*dvn,
                              accE[i][1]*dvn, accO[i][1]*dvn);
      float4 o1 = make_float4(accE[i][2]*dvn, accO[i][2]*dvn,
                              accE[i][3]*dvn, accO[i][3]*dvn);
      *(float4*)(C + (size_t)r*512 + 2*c0)     = o0;
      *(float4*)(C + (size_t)r*512 + 2*c0 + 4) = o1;
    } else if constexpr (OP==2){
      int d = r % DD;
      float w = p0[d], bo = p1[d];           // Af / Cf
      float d0e = (c0==0) ? dv0 : dvn;
      float4 o0 = make_float4(gelu_f(accE[i][0]*d0e)*w+bo,
                              gelu_f(accO[i][0]*dvn)*w+bo,
                              gelu_f(accE[i][1]*dvn)*w+bo,
                              gelu_f(accO[i][1]*dvn)*w+bo);
      float4 o1 = make_float4(gelu_f(accE[i][2]*dvn)*w+bo,
                              gelu_f(accO[i][2]*dvn)*w+bo,
                              gelu_f(accE[i][3]*dvn)*w+bo,
                              gelu_f(accO[i][3]*dvn)*w+bo);
      *(float4*)(C + (size_t)r*512 + 2*c0)     = o0;
      *(float4*)(C + (size_t)r*512 + 2*c0 + 4) = o1;
    } else {   // OP==1, l = c0..c0+3 and mirrors 511-l
      int d = r % DD;
      float w = p0[d], bo = p1[d];           // conv1_w / conv1_b
      float4 xf = *(const float4*)(p2 + (size_t)r*512 + c0);
      float4 xr = *(const float4*)(p2 + (size_t)r*512 + 508 - c0);
      float4 of, orv;
      of.x = accE[i][0]+accO[i][0] + xf.x*w+bo;
      of.y = accE[i][1]+accO[i][1] + xf.y*w+bo;
      of.z = accE[i][2]+accO[i][2] + xf.z*w+bo;
      of.w = accE[i][3]+accO[i][3] + xf.w*w+bo;
      orv.x = accE[i][3]-accO[i][3] + xr.x*w+bo;
      orv.y = accE[i][2]-accO[i][2] + xr.y*w+bo;
      orv.z = accE[i][1]-accO[i][1] + xr.z*w+bo;
      orv.w = accE[i][0]-accO[i][0] + xr.w*w+bo;
      *(float4*)(C + (size_t)r*512 + c0)       = of;
      *(float4*)(C + (size_t)r*512 + 508 - c0) = orv;
    }
  }
}

// ---------------- merged 96-col GEMMs: h (zf blend) and zres ----------------
// blockIdx.z==0: A = z1c*att + z2*(1-att) (fused zf), B=fc1T, C=h=gelu(.+b).
// blockIdx.z==1: A = xt, B=WeffT, C=zres=.+cres.
// 64 rows x 64 cols, 128 threads, 8x4 micro-tile.
__global__ __launch_bounds__(128, 4)
void gemm96(const float* __restrict__ z1c, const float* __restrict__ z2,
            const float* __restrict__ att1, const float* __restrict__ xt,
            const float* __restrict__ fc1T, const float* __restrict__ WeffT,
            float* __restrict__ h, float* __restrict__ zres,
            const float* __restrict__ fc1_b, const float* __restrict__ cres, int M)
{
  __shared__ float As[32][68];
  __shared__ float Bs[32][68];
  __shared__ float att_s[64];
  const int tid = threadIdx.x;
  const int tx = tid & 15, ty = tid >> 4;         // tx: 16 col-grp, ty: 8 row-grp
  const int rb = blockIdx.y * 64, cb = blockIdx.x * 64;
  const int z = blockIdx.z;
  const float* Bmat = z ? WeffT : fc1T;

  if (z==0 && tid < 64){
    int r = rb + tid;
    att_s[tid] = (r < M) ? att1[r] : 0.f;
  }
  __syncthreads();

  float acc[8][4];
  #pragma unroll
  for (int i=0;i<8;i++)
    #pragma unroll
    for (int j=0;j<4;j++) acc[i][j]=0.f;

  for (int kb=0; kb<512; kb+=32){
    #pragma unroll
    for (int i=0;i<4;i++){
      int idx = tid + i*128;                // 512: 64 rows x 8 float4
      int row = idx >> 3, k4 = (idx & 7)*4;
      int r = rb + row;
      float4 v = make_float4(0.f,0.f,0.f,0.f);
      if (r < M){
        if (z==0){
          float4 v1 = *(const float4*)(z1c + (size_t)r*512 + kb + k4);
          float4 v2 = *(const float4*)(z2  + (size_t)r*512 + kb + k4);
          float a = att_s[row];
          v.x = v2.x + a*(v1.x - v2.x);
          v.y = v2.y + a*(v1.y - v2.y);
          v.z = v2.z + a*(v1.z - v2.z);
          v.w = v2.w + a*(v1.w - v2.w);
        } else {
          v = *(const float4*)(xt + (size_t)r*512 + kb + k4);
        }
      }
      As[k4+0][row]=v.x; As[k4+1][row]=v.y; As[k4+2][row]=v.z; As[k4+3][row]=v.w;
    }
    #pragma unroll
    for (int i=0;i<4;i++){
      int idx = tid + i*128;                // 512: 64 cols x 8 float4
      int crow = idx >> 3, k4 = (idx & 7)*4;
      int c = cb + crow;
      float4 v = make_float4(0.f,0.f,0.f,0.f);
      if (c < 96) v = *(const float4*)(Bmat + (size_t)c*512 + kb + k4);
      Bs[k4+0][crow]=v.x; Bs[k4+1][crow]=v.y; Bs[k4+2][crow]=v.z; Bs[k4+3][crow]=v.w;
    }
    __syncthreads();
    #pragma unroll
    for (int kk=0; kk<32; kk++){
      const float4 a0 = *(const float4*)&As[kk][ty*8];
      const float4 a1 = *(const float4*)&As[kk][ty*8+4];
      const float4 b0 = *(const float4*)&Bs[kk][tx*4];
      float av[8]={a0.x,a0.y,a0.z,a0.w,a1.x,a1.y,a1.z,a1.w};
      float bv[4]={b0.x,b0.y,b0.z,b0.w};
      #pragma unroll
      for (int i=0;i<8;i++)
        #pragma unroll
        for (int j=0;j<4;j++) acc[i][j]=fmaf(av[i],bv[j],acc[i][j]);
    }
    __syncthreads();
  }

  #pragma unroll
  for (int i=0;i<8;i++){
    const int r = rb + ty*8 + i;
    if (r >= M) continue;
    #pragma unroll
    for (int j=0;j<4;j++){
      int c = cb + tx*4 + j;
      if (c < 96){
        if (z==0) h[(size_t)r*96 + c]    = gelu_f(acc[i][j] + fc1_b[c]);
        else      zres[(size_t)r*96 + c] = acc[i][j] + cres[c];
      }
    }
  }
}

// ---------------- energy per row (deterministic) ----------------------------
__global__ __launch_bounds__(256)
void k_energy(const float* __restrict__ zdct, float* __restrict__ energy)
{
  int r=blockIdx.x, tid=threadIdx.x;
  __shared__ float rbuf[256];
  float acc=0.f;
  for (int k=tid;k<512;k+=256){ float v=zdct[(size_t)r*512+k]; acc=fmaf(v,v,acc); }
  rbuf[tid]=acc; __syncthreads();
  for (int st=128;st>0;st>>=1){ if(tid<st) rbuf[tid]+=rbuf[tid+st]; __syncthreads(); }
  if (tid==0) energy[r]=rbuf[0];
}

// ---------------- median over D per batch, ne = e/(med+1e-6) ----------------
__global__ __launch_bounds__(256)
void k3_median(const float* __restrict__ energy, float* __restrict__ ne)
{
  int b = blockIdx.x, tid=threadIdx.x;
  __shared__ float e[DD];
  __shared__ float medv;
  for (int i=tid;i<DD;i+=256) e[i]=energy[b*DD+i];
  __syncthreads();
  for (int i=tid;i<DD;i+=256){
    float v=e[i]; int lt=0, eq=0;
    for (int j=0;j<DD;j++){ float u=e[j]; lt += (u<v); eq += (u==v); }
    if (lt<=160 && 160<lt+eq) medv=v;      // 0-based rank 160 of 321
  }
  __syncthreads();
  float den = medv + 1e-6f;
  for (int i=tid;i<DD;i+=256) ne[b*DD+i] = e[i]/den;
}

// ---------------- quantile via radix select (2 ranks + lerp) ----------------
__global__ __launch_bounds__(1024)
void k3_thr(const float* __restrict__ ne, const float* __restrict__ thrin,
            float* __restrict__ out)
{
  __shared__ int hist[256];
  __shared__ unsigned sPrefix; __shared__ int sRank;
  int tid = threadIdx.x;
  float q = fminf(fmaxf(thrin[0],0.f),1.f);
  float pos = q * (float)(M_ROWS-1);
  int lo = (int)floorf(pos); int hi = (int)ceilf(pos);
  float frac = pos - floorf(pos);
  float vals[2];
  for (int s=0;s<2;s++){
    int rank = s ? hi : lo;
    unsigned prefix=0, pmask=0;
    for (int pass=0; pass<4; pass++){
      int shift = 24 - 8*pass;
      if (tid<256) hist[tid]=0;
      __syncthreads();
      for (int i=tid;i<M_ROWS;i+=1024){
        unsigned u = __float_as_uint(ne[i]);
        if ((u & pmask)==prefix) atomicAdd(&hist[(u>>shift)&255u],1);
      }
      __syncthreads();
      if (tid==0){
        int cum=0;
        for (int bkt=0;bkt<256;bkt++){
          int c=hist[bkt];
          if (cum + c > rank){ sPrefix = prefix | ((unsigned)bkt<<(unsigned)shift); sRank = rank - cum; break; }
          cum += c;
        }
      }
      __syncthreads();
      prefix = sPrefix; rank = sRank; pmask |= (0xFFu<<(unsigned)shift);
      __syncthreads();
    }
    vals[s] = __uint_as_float(prefix);
  }
  if (tid==0) out[0] = vals[0]*(1.0f-frac) + vals[1]*frac;
}

// ---------------- in-place transform of zdct before IDCT --------------------
__global__ void k4_pre(float* __restrict__ zdct, const float* __restrict__ ne,
                       const float* __restrict__ thr, const float* __restrict__ w1,
                       const float* __restrict__ b1, const float* __restrict__ dvec)
{
  size_t idx = (size_t)blockIdx.x*256 + threadIdx.x;   // over 10272*128 float4
  int r = (int)(idx>>7);
  int k0 = ((int)idx & 127)*4;
  float m  = (ne[r] > thr[0]) ? 1.f : 0.f;
  int d = r % DD;
  float w = w1[d]*m, bo = b1[d];
  float4 v = ((float4*)zdct)[idx];
  v.x = gelu_f(fmaf(v.x,w,bo))/dvec[k0+0];
  v.y = gelu_f(fmaf(v.y,w,bo))/dvec[k0+1];
  v.z = gelu_f(fmaf(v.z,w,bo))/dvec[k0+2];
  v.w = gelu_f(fmaf(v.w,w,bo))/dvec[k0+3];
  ((float4*)zdct)[idx]=v;
}

// ---------------- z2: per-patch 16x16 matmul + gelu -------------------------
__global__ __launch_bounds__(256)
void k5_z2(const float* __restrict__ xt, const float* __restrict__ Mp,
           const float* __restrict__ c2p, float* __restrict__ z2)
{
  int r = blockIdx.x, tid=threadIdx.x;
  __shared__ float row[512];
  for (int i=tid;i<512;i+=256) row[i]=xt[(size_t)r*512+i];
  __syncthreads();
  for (int idx=tid; idx<512; idx+=256){
    int n = idx>>4, p = idx&15;
    float acc = c2p[idx];
    const float* Mn = Mp + n*256 + p;
    #pragma unroll
    for (int qq=0;qq<16;qq++) acc = fmaf(row[n*16+qq], Mn[qq*16], acc);
    z2[(size_t)r*512+idx] = gelu_f(acc);
  }
}

// ---------------- fused convs / gates / z1c / att-dot -----------------------
__global__ __launch_bounds__(256)
void k7_fuse(const float* __restrict__ z1, const float* __restrict__ z2f,
             const float* __restrict__ z2, float* __restrict__ z1c,
             float* __restrict__ zdpre,
             const float* __restrict__ c2w, const float* __restrict__ c2b,
             const float* __restrict__ c3w, const float* __restrict__ c3b,
             const float* __restrict__ Af,  const float* __restrict__ Cf,
             const float* __restrict__ dns, const float* __restrict__ Bf,
             const float* __restrict__ catt)
{
  int r = blockIdx.x, tid=threadIdx.x;
  int d = r % DD;
  __shared__ float zrow[518];
  __shared__ float rbuf[256];
  for (int i=tid;i<518;i+=256){
    int l = i-3;
    zrow[i] = (l>=0 && l<512) ? z1[(size_t)r*512+l] : 0.f;
  }
  __syncthreads();
  float w2[5], w3[7];
  #pragma unroll
  for (int t=0;t<5;t++) w2[t]=c2w[d*5+t];
  #pragma unroll
  for (int t=0;t<7;t++) w3[t]=c3w[d*7+t];
  const float cb2=c2b[d], cb3=c3b[d];
  const float af=Af[d], cf=Cf[d], s=dns[d], bf=Bf[d];
  float dotacc=0.f;
  for (int l=tid;l<512;l+=256){
    float c5=cb2;
    #pragma unroll
    for (int t=0;t<5;t++) c5 = fmaf(zrow[l+t+1], w2[t], c5);   // pad-2 conv k=5
    float zr  = sigmoid_f(fmaf(gelu_f(c5),af,cf));
    float zgv = gelu_f(z2f[(size_t)r*512+l]*zr);
    float c7=cb3;
    #pragma unroll
    for (int t=0;t<7;t++) c7 = fmaf(zrow[l+t], w3[t], c7);     // pad-3 conv k=7
    float z1b = gelu_f(fmaf(c7,s,bf));
    float v = fmaf(zgv,s,bf) + z1b;                            // z1c = bnD(zg)+z1b
    z1c[(size_t)r*512+l]=v;
    dotacc = fmaf(v*z2[(size_t)r*512+l], catt[l], dotacc);
  }
  rbuf[tid]=dotacc; __syncthreads();
  for (int st=128;st>0;st>>=1){ if(tid<st) rbuf[tid]+=rbuf[tid+st]; __syncthreads(); }
  if (tid==0) zdpre[r]=rbuf[0];
}

// ---------------- attention scalar path + softmax over D --------------------
__global__ __launch_bounds__(256)
void k8_att(const float* __restrict__ zdpre, float* __restrict__ att1,
            const float* __restrict__ adwb, const float* __restrict__ acw,
            const float* __restrict__ acb,  const float* __restrict__ ag,
            const float* __restrict__ ab,   const float* __restrict__ am,
            const float* __restrict__ av)
{
  int b=blockIdx.x, t=threadIdx.x;
  __shared__ float sred[256];
  float vloc[2];
  float mx=-INFINITY;
  float sA = ag[0]/sqrtf(av[0]+1e-5f);
  #pragma unroll
  for (int ii=0;ii<2;ii++){
    int d=t+ii*256;
    float v=-INFINITY;
    if (d<DD){
      float zd = zdpre[b*DD+d] + adwb[0];
      zd = gelu_f(zd);
      zd = (zd-am[0])*sA + ab[0];
      zd = zd*acw[0] + acb[0];
      v=zd;
    }
    vloc[ii]=v; mx=fmaxf(mx,v);
  }
  sred[t]=mx; __syncthreads();
  for (int st=128;st>0;st>>=1){ if (t<st) sred[t]=fmaxf(sred[t],sred[t+st]); __syncthreads(); }
  float m=sred[0]; __syncthreads();
  float e0 = (t<DD)     ? expf(vloc[0]-m) : 0.f;
  float e1 = (t+256<DD) ? expf(vloc[1]-m) : 0.f;
  sred[t]=e0+e1; __syncthreads();
  for (int st=128;st>0;st>>=1){ if (t<st) sred[t]+=sred[t+st]; __syncthreads(); }
  float sum=sred[0];
  if (t<DD)     att1[b*DD+t]     = e0/sum;
  if (t+256<DD) att1[b*DD+t+256] = e1/sum;
}

// ---------------- final: out = h@fc2 + fc2_b + zres, transposed store -------
__global__ __launch_bounds__(256)
void k9_final(const float* __restrict__ h, const float* __restrict__ zres,
              const float* __restrict__ fc2_w, const float* __restrict__ fc2_b,
              float* __restrict__ outF)
{
  int b = blockIdx.y; int d0 = blockIdx.x*32;
  __shared__ float f2[96*96];
  __shared__ float hs[32][97];
  __shared__ float zs[32][97];
  int tid=threadIdx.x;
  for (int i=tid;i<96*96;i+=256) f2[i]=fc2_w[i];
  for (int i=tid;i<32*96;i+=256){
    int dl = i/96, p = i%96; int d = d0+dl;
    float hv=0.f, zv=0.f;
    if (d<DD){ hv = h[((size_t)b*DD+d)*96+p]; zv = zres[((size_t)b*DD+d)*96+p]; }
    hs[dl][p]=hv; zs[dl][p]=zv;
  }
  __syncthreads();
  int tx = tid & 31, ty = tid >> 5;
  int d = d0+tx;
  float acc[12];
  #pragma unroll
  for (int kc=0;kc<12;kc++) acc[kc]=0.f;
  for (int p=0;p<96;p++){
    float hv = hs[tx][p];
    #pragma unroll
    for (int kc=0;kc<12;kc++) acc[kc] = fmaf(hv, f2[p*96 + ty + kc*8], acc[kc]);
  }
  if (d<DD){
    #pragma unroll
    for (int kc=0;kc<12;kc++){
      int c = ty + kc*8;
      outF[((size_t)b*96 + c)*DD + d] = acc[kc] + fc2_b[c] + zs[tx][c];
    }
  }
}

// ---------------------------------------------------------------------------
extern "C" void kernel_launch(void* const* d_in, const int* in_sizes, int n_in,
                              void* d_out, int out_size, void* d_ws, size_t ws_size,
                              hipStream_t stream)
{
  (void)in_sizes; (void)n_in; (void)out_size; (void)ws_size;
  const float* x        =(const float*)d_in[0];
  const float* conv1_w  =(const float*)d_in[1];
  const float* conv1_b  =(const float*)d_in[2];
  const float* conv2_w  =(const float*)d_in[3];
  const float* conv2_b  =(const float*)d_in[4];
  const float* conv3_w  =(const float*)d_in[5];
  const float* conv3_b  =(const float*)d_in[6];
  const float* dn_g     =(const float*)d_in[7];
  const float* dn_b     =(const float*)d_in[8];
  const float* dn_m     =(const float*)d_in[9];
  const float* dn_v     =(const float*)d_in[10];
  const float* pn_g     =(const float*)d_in[11];
  const float* pn_b     =(const float*)d_in[12];
  const float* pn_m     =(const float*)d_in[13];
  const float* pn_v     =(const float*)d_in[14];
  const float* embed_w  =(const float*)d_in[15];
  const float* embed_b  =(const float*)d_in[16];
  const float* lin_res_w=(const float*)d_in[17];
  const float* lin_res_b=(const float*)d_in[18];
  const float* depth_res_w=(const float*)d_in[19];
  const float* depth_res_b=(const float*)d_in[20];
  const float* depth_conv_w=(const float*)d_in[21];
  const float* depth_conv_b=(const float*)d_in[22];
  const float* threshold=(const float*)d_in[23];
  const float* att_dw_w =(const float*)d_in[24];
  const float* att_dw_b =(const float*)d_in[25];
  const float* att_conv_w=(const float*)d_in[26];
  const float* att_conv_b=(const float*)d_in[27];
  const float* att_g    =(const float*)d_in[28];
  const float* att_b    =(const float*)d_in[29];
  const float* att_m    =(const float*)d_in[30];
  const float* att_v    =(const float*)d_in[31];
  const float* fc1_w    =(const float*)d_in[32];
  const float* fc1_b    =(const float*)d_in[33];
  const float* fc2_w    =(const float*)d_in[34];
  const float* fc2_b    =(const float*)d_in[35];

  float* ws   = (float*)d_ws;
  float* CoE  = ws + OFF_COE;
  float* CoO  = ws + OFF_COO;
  float* CoET = ws + OFF_COET;
  float* CoOT = ws + OFF_COOT;
  float* dvec = ws + OFF_DVEC;
  float* catt = ws + OFF_CATT;
  float* fc1T = ws + OFF_FC1T;
  float* WeffT= ws + OFF_WEFFT;
  float* cres = ws + OFF_CRES;
  float* Mp   = ws + OFF_MP;
  float* c2p  = ws + OFF_C2P;
  float* Af   = ws + OFF_AF;
  float* Cf   = ws + OFF_CF;
  float* dns  = ws + OFF_DNS;
  float* Bf   = ws + OFF_BF;
  float* energy=ws + OFF_EN;
  float* ne   = ws + OFF_NE;
  float* thr  = ws + OFF_THR;
  float* zdpre= ws + OFF_ZDP;
  float* att1 = ws + OFF_ATT1;
  float* xt   = ws + OFF_XT;
  float* zdct = ws + OFF_ZDCT;   // later reused as z2f
  float* z1   = ws + OFF_Z1;
  float* z2   = ws + OFF_Z2;
  float* z1c  = ws + OFF_Z1C;
  float* h    = ws + OFF_H;
  float* zres = ws + OFF_ZRES;
  float* Wpart= ws + OFF_WPART;
  float* pcres= ws + OFF_PCRES;

  // --- precompute ---
  k0_dctF <<<256, 256, 0, stream>>>(CoE, CoO, CoET, CoOT, dvec, catt, att_dw_w);
  kA_weff <<<dim3(32,4), 256, 0, stream>>>(embed_w, embed_b, lin_res_w, Wpart, pcres);
  kA_fin  <<<193, 256, 0, stream>>>(Wpart, pcres, lin_res_b, WeffT, cres);
  kT_fc1  <<<dim3(3,16), 256, 0, stream>>>(fc1_w, fc1T);
  k0_depth<<<32, 256, 0, stream>>>(embed_w, embed_b, depth_res_w, depth_res_b,
                                   depth_conv_w, depth_conv_b, pn_g, pn_b, pn_m, pn_v,
                                   Mp, c2p);
  k0_fold <<<2, 256, 0, stream>>>(conv1_w, conv1_b, dn_g, dn_b, dn_m, dn_v,
                                  Af, Cf, dns, Bf);

  // --- transpose, DCT(x), mask stats ---
  k1_transpose<<<dim3(11,16,BB), 256, 0, stream>>>(x, xt);
  gemm_dual<0><<<dim3(8,161), 128, 0, stream>>>(xt, CoE, CoO, zdct, M_ROWS,
                                                nullptr, nullptr, nullptr);
  k_energy <<<M_ROWS, 256, 0, stream>>>(zdct, energy);
  k3_median<<<BB, 256, 0, stream>>>(energy, ne);
  k3_thr   <<<1, 1024, 0, stream>>>(ne, threshold, thr);

  // --- z1 = idct(gelu(conv1(mask*zdct))) + freq_res ---
  k4_pre   <<<5136, 256, 0, stream>>>(zdct, ne, thr, conv1_w, conv1_b, dvec);
  gemm_dual<1><<<dim3(8,161), 128, 0, stream>>>(zdct, CoET, CoOT, z1, M_ROWS,
                                                conv1_w, conv1_b, xt);
  // --- z2 (patch path), z2_f = conv1(bnD(gelu(dct(z2)))) into zdct buf ---
  k5_z2    <<<M_ROWS, 256, 0, stream>>>(xt, Mp, c2p, z2);
  gemm_dual<2><<<dim3(8,161), 128, 0, stream>>>(z2, CoE, CoO, zdct, M_ROWS,
                                                Af, Cf, nullptr);

  // --- convs, gates, z1c, att-dot ---
  k7_fuse  <<<M_ROWS, 256, 0, stream>>>(z1, zdct, z2, z1c, zdpre,
                                        conv2_w, conv2_b, conv3_w, conv3_b,
                                        Af, Cf, dns, Bf, catt);
  k8_att   <<<BB, 256, 0, stream>>>(zdpre, att1, att_dw_b, att_conv_w, att_conv_b,
                                    att_g, att_b, att_m, att_v);

  // --- MLP head (zf fused into staging) + linear residual ---
  gemm96   <<<dim3(2,161,2), 128, 0, stream>>>(z1c, z2, att1, xt, fc1T, WeffT,
                                               h, zres, fc1_b, cres, M_ROWS);
  k9_final <<<dim3(11,BB), 256, 0, stream>>>(h, zres, fc2_w, fc2_b, (float*)d_out);
}